// Round 1
// baseline (244.806 us; speedup 1.0000x reference)
//
#include <hip/hip_runtime.h>
#include <hip/hip_bf16.h>

// B=4, S=1024, D=1024, H=16, HD=64 — tokens M=4096, feature K=1024
// fp32 inputs -> bf16 convert pass -> all GEMMs/attention in bf16 MFMA
// (fp32 accumulate) -> fp32 output.
// THIS ROUND: proj GEMMs ported from m97 2-barrier structure (585 TF,
// MfmaUtil 23%) to the 8-phase counted-vmcnt template (T2 st_16x32 swizzle +
// T3/T4 counted vmcnt + T5 setprio). BM=128 BN=256 BK=64, 8 waves,
// 2-deep LDS dbuf (96 KiB), 1 block/CU. keff blocks (3 gathered terms,
// same fp32 accumulator => identical numerics) dispatched first (3x work).
// Attention / out-proj / cvt unchanged this round.

typedef __bf16 bf16x8 __attribute__((ext_vector_type(8)));
typedef __bf16 bf16x4 __attribute__((ext_vector_type(4)));
typedef float  f32x4  __attribute__((ext_vector_type(4)));

#define DMODEL 1024

#define ASYNC_LOAD16(gp, lp)                                                  \
    __builtin_amdgcn_global_load_lds(                                         \
        (const __attribute__((address_space(1))) unsigned int*)(gp),          \
        (__attribute__((address_space(3))) unsigned int*)(lp), 16, 0, 0)

// ---------------------------------------------------------------------------
// fp32 -> bf16 conversion: x (4M) + 6 weights (1M each); Wbar pre-scaled by
// 0.2 and Wbeat by 0.1 (folds the score-bias scales into the GEMM).
// ---------------------------------------------------------------------------
__global__ __launch_bounds__(256) void cvt_kernel(
    const float* __restrict__ x,
    const float* __restrict__ Wq, const float* __restrict__ Wk,
    const float* __restrict__ Wv, const float* __restrict__ Wbar,
    const float* __restrict__ Wbeat, const float* __restrict__ Wo,
    __bf16* __restrict__ dst)
{
    const int g = blockIdx.x * 256 + threadIdx.x;
    const size_t e = (size_t)g * 8;
    const int seg = (int)(e >> 20);
    const float* src; size_t off; float s = 1.0f;
    if (seg < 4)       { src = x;     off = e; }
    else if (seg == 4) { src = Wq;    off = e - ((size_t)4 << 20); }
    else if (seg == 5) { src = Wk;    off = e - ((size_t)5 << 20); }
    else if (seg == 6) { src = Wv;    off = e - ((size_t)6 << 20); }
    else if (seg == 7) { src = Wbar;  off = e - ((size_t)7 << 20); s = 0.2f; }
    else if (seg == 8) { src = Wbeat; off = e - ((size_t)8 << 20); s = 0.1f; }
    else               { src = Wo;    off = e - ((size_t)9 << 20); }
    const float4 a = *(const float4*)&src[off];
    const float4 b = *(const float4*)&src[off + 4];
    bf16x8 v;
    v[0] = (__bf16)(a.x * s); v[1] = (__bf16)(a.y * s);
    v[2] = (__bf16)(a.z * s); v[3] = (__bf16)(a.w * s);
    v[4] = (__bf16)(b.x * s); v[5] = (__bf16)(b.y * s);
    v[6] = (__bf16)(b.z * s); v[7] = (__bf16)(b.w * s);
    *(bf16x8*)&dst[e] = v;
}

// ---------------------------------------------------------------------------
// 8-phase GEMM (m201-style template, plain HIP):
//   BM=128, BN=256, BK=64, 512 threads = 8 waves (2M x 4N), wave tile 64x64
//   (split as two 32-row chunks, one per A-half; two 32-col chunks, one per
//   B-half => every wave consumes halves in the same staggered order).
//   LDS: A 2x[128][64] (32KB) + B 2x[256][64] (64KB) = 96KB, linear layout
//   for global_load_lds; st_16x32 swizzle via pre-swizzled SOURCE address +
//   swizzled ds_read (involution o ^= ((o>>9)&1)<<5, rule #21).
//   Per K-tile: 4 phases = C-quadrants (0,0),(0,1),(1,1),(1,0); each phase
//   {ds_read new half-frags; issue 1 half-tile stage of tile t+1; barrier;
//    lgkmcnt(0); setprio(1); 8 MFMA; setprio(0); counted vmcnt; barrier}.
//   Stage issue order per tile: A0(1 load), B0(2), B1(2), A1(1).
//   Steady-state waits {ph0:vmcnt(2), ph1:vmcnt(3), ph2:-, ph3:vmcnt(3)},
//   never 0 in main loop; last tile drains {1,0,-,-}.
// Block map: bid 0..127 keff (3 terms: Wk + gather_bar@0.2Wbar +
//   gather_beat@0.1Wbeat, ONE fp32 acc over 48 K-tiles — same numerics as
//   before), 128..255 q (bias+0.125 scale), 256..383 v (transposed store).
// ---------------------------------------------------------------------------

#define SWZ_COL(r_, ks_) \
    (((((ks_) * 64) + quad * 16) ^ ((((r_) >> 2) & 1) << 5)) >> 1)

#define READ_A(c_, mh_)                                                       \
    do {                                                                      \
        _Pragma("unroll") for (int mi = 0; mi < 2; ++mi) {                    \
            const int r_ = ((w >> 2) << 5) + (mh_) * 64 + mi * 16 + l15;      \
            _Pragma("unroll") for (int ks = 0; ks < 2; ++ks)                  \
                af[mi][ks] = *(const bf16x8*)&Alds[(c_) * 8192 + r_ * 64 +    \
                                                   SWZ_COL(r_, ks)];          \
        }                                                                     \
    } while (0)

#define READ_B(c_, nh_)                                                       \
    do {                                                                      \
        _Pragma("unroll") for (int nj = 0; nj < 2; ++nj) {                    \
            const int r_ = ((w & 3) << 5) + (nh_) * 128 + nj * 16 + l15;      \
            _Pragma("unroll") for (int ks = 0; ks < 2; ++ks)                  \
                bf[nj][ks] = *(const bf16x8*)&Blds[(c_) * 16384 + r_ * 64 +   \
                                                    SWZ_COL(r_, ks)];         \
        }                                                                     \
    } while (0)

#define STAGE_A8(bufn_, h_, kt_)                                              \
    do {                                                                      \
        const int tm_ = (kt_) >> 4;                                           \
        const int k0_ = ((kt_) & 15) << 6;                                    \
        const __bf16* ap_ = (tm_ == 0) ? aA0##h_ : (tm_ == 1) ? aA1##h_       \
                                                              : aA2##h_;      \
        ASYNC_LOAD16(ap_ + k0_,                                               \
                     &Alds[(bufn_) * 8192 + (h_) * 4096 + w * 512]);          \
    } while (0)

#define STAGE_B8(bufn_, h_, kt_)                                              \
    do {                                                                      \
        const int tm_ = (kt_) >> 4;                                           \
        const int k0_ = ((kt_) & 15) << 6;                                    \
        const __bf16* wp_ = (tm_ == 0) ? W0 : (tm_ == 1) ? W1 : W2;           \
        ASYNC_LOAD16(wp_ + bro##h_##0 + k0_,                                  \
                     &Blds[(bufn_) * 16384 + (h_) * 8192 + w * 512]);         \
        ASYNC_LOAD16(wp_ + bro##h_##1 + k0_,                                  \
                     &Blds[(bufn_) * 16384 + (h_) * 8192 + 4096 + w * 512]);  \
    } while (0)

#define PHASE_BAR1()                                                          \
    do {                                                                      \
        __builtin_amdgcn_s_barrier();                                         \
        asm volatile("s_waitcnt lgkmcnt(0)" ::: "memory");                    \
    } while (0)

#define MFMA8(mh_, nh_)                                                       \
    do {                                                                      \
        __builtin_amdgcn_s_setprio(1);                                        \
        _Pragma("unroll") for (int mi = 0; mi < 2; ++mi)                      \
        _Pragma("unroll") for (int nj = 0; nj < 2; ++nj) {                    \
            acc[(mh_)*2 + mi][(nh_)*2 + nj] =                                 \
                __builtin_amdgcn_mfma_f32_16x16x32_bf16(                      \
                    af[mi][0], bf[nj][0], acc[(mh_)*2 + mi][(nh_)*2 + nj],    \
                    0, 0, 0);                                                 \
            acc[(mh_)*2 + mi][(nh_)*2 + nj] =                                 \
                __builtin_amdgcn_mfma_f32_16x16x32_bf16(                      \
                    af[mi][1], bf[nj][1], acc[(mh_)*2 + mi][(nh_)*2 + nj],    \
                    0, 0, 0);                                                 \
        }                                                                     \
        __builtin_amdgcn_s_setprio(0);                                        \
    } while (0)

__global__ __launch_bounds__(512, 2) void gemm8p_kernel(
    const __bf16* __restrict__ xb,
    const __bf16* __restrict__ Wqb, const __bf16* __restrict__ Wkb,
    const __bf16* __restrict__ Wvb, const __bf16* __restrict__ Wbarb,
    const __bf16* __restrict__ Wbeatb,
    const float* __restrict__ bq, const float* __restrict__ bk,
    const float* __restrict__ bv, const float* __restrict__ bbar,
    const float* __restrict__ bbeat,
    const int* __restrict__ bar_idx, const int* __restrict__ beat_idx,
    __bf16* __restrict__ qbuf, __bf16* __restrict__ keffbuf,
    __bf16* __restrict__ vtbuf)
{
    __shared__ __align__(16) __bf16 Alds[2 * 8192];    // 2 buf x [128][64]
    __shared__ __align__(16) __bf16 Blds[2 * 16384];   // 2 buf x [256][64]

    const int bid = blockIdx.x;
    int mode, tk;
    if (bid < 128)      { mode = 1; tk = bid; }        // keff first (3x work)
    else if (bid < 256) { mode = 0; tk = bid - 128; }  // q
    else                { mode = 2; tk = bid - 256; }  // v
    const int m0 = (tk >> 2) << 7;                     // 32 m-tiles x 128
    const int n0 = (tk & 3) << 8;                      // 4 n-tiles x 256
    const int nkt = (mode == 1) ? 48 : 16;

    const int t    = (int)threadIdx.x;
    const int w    = t >> 6;
    const int lane = t & 63;
    const int l15  = lane & 15;
    const int quad = lane >> 4;

    // staging geometry: thread stages 16B at linear LDS byte o = h*HBYTES +
    // (li*8192) + t*16; row = o>>7, source col pre-swizzled so that the
    // linear LDS slot receives the element the swizzled ds_read expects.
    const int srow = t >> 3;                                    // 0..63
    const int scol = ((((t & 7) * 16) ^ (((t >> 5) & 1) << 5)) >> 1);

    const __bf16* aA00 = xb + (size_t)(m0 + srow) * DMODEL + scol;
    const __bf16* aA01 = xb + (size_t)(m0 + 64 + srow) * DMODEL + scol;
    const __bf16* aA10 = aA00; const __bf16* aA11 = aA01;
    const __bf16* aA20 = aA00; const __bf16* aA21 = aA01;
    const __bf16 *W0, *W1, *W2;
    if (mode == 0)      { W0 = W1 = W2 = Wqb; }
    else if (mode == 2) { W0 = W1 = W2 = Wvb; }
    else {
        W0 = Wkb; W1 = Wbarb; W2 = Wbeatb;
        const int bb = m0 & ~1023;                 // batch base row
        const int lr = m0 & 1023;                  // seq-local tile base
        aA10 = xb + (size_t)(bb + bar_idx[lr + srow]) * DMODEL + scol;
        aA11 = xb + (size_t)(bb + bar_idx[lr + 64 + srow]) * DMODEL + scol;
        aA20 = xb + (size_t)(bb + beat_idx[lr + srow]) * DMODEL + scol;
        aA21 = xb + (size_t)(bb + beat_idx[lr + 64 + srow]) * DMODEL + scol;
    }
    const size_t bro00 = (size_t)(n0 + srow) * DMODEL + scol;
    const size_t bro01 = (size_t)(n0 + 64 + srow) * DMODEL + scol;
    const size_t bro10 = (size_t)(n0 + 128 + srow) * DMODEL + scol;
    const size_t bro11 = (size_t)(n0 + 192 + srow) * DMODEL + scol;

    f32x4 acc[4][4];
#pragma unroll
    for (int i = 0; i < 4; ++i)
#pragma unroll
        for (int j = 0; j < 4; ++j)
            acc[i][j] = {0.f, 0.f, 0.f, 0.f};
    bf16x8 af[2][2], bf[2][2];

    // prologue: stage tile 0 in issue order [A0, B0x2, B1x2, A1]; publish
    // A0/B0 (oldest 3) and enter steady state with [B1x2, A1] in flight.
    STAGE_A8(0, 0, 0);
    asm volatile("" ::: "memory");
    STAGE_B8(0, 0, 0);
    asm volatile("" ::: "memory");
    STAGE_B8(0, 1, 0);
    asm volatile("" ::: "memory");
    STAGE_A8(0, 1, 0);
    asm volatile("s_waitcnt vmcnt(3)" ::: "memory");
    __builtin_amdgcn_s_barrier();

#pragma unroll 1
    for (int kt = 0; kt < nkt - 1; ++kt) {
        const int c  = kt & 1;
        const int nb = c ^ 1;
        const int kn = kt + 1;

        // ph0: quadrant (0,0) — reads A0,B0(t); stages A0(t+1)
        READ_A(c, 0);
        READ_B(c, 0);
        STAGE_A8(nb, 0, kn);
        PHASE_BAR1();
        MFMA8(0, 0);
        asm volatile("s_waitcnt vmcnt(2)" ::: "memory");  // B1(t) landed
        __builtin_amdgcn_s_barrier();

        // ph1: quadrant (0,1) — reads B1(t); stages B0(t+1)
        READ_B(c, 1);
        STAGE_B8(nb, 0, kn);
        PHASE_BAR1();
        MFMA8(0, 1);
        asm volatile("s_waitcnt vmcnt(3)" ::: "memory");  // A1(t) landed
        __builtin_amdgcn_s_barrier();

        // ph2: quadrant (1,1) — reads A1(t); stages B1(t+1)
        READ_A(c, 1);
        STAGE_B8(nb, 1, kn);
        PHASE_BAR1();
        MFMA8(1, 1);
        __builtin_amdgcn_s_barrier();                     // no wait needed

        // ph3: quadrant (1,0) — re-reads B0(t); stages A1(t+1)
        READ_B(c, 0);
        STAGE_A8(nb, 1, kn);
        PHASE_BAR1();
        MFMA8(1, 0);
        asm volatile("s_waitcnt vmcnt(3)" ::: "memory");  // A0,B0(t+1) landed
        __builtin_amdgcn_s_barrier();
    }

    // last tile (no staging): drain waits 1 -> 0
    {
        const int c = (nkt - 1) & 1;   // always 1 (nkt = 16 or 48)
        READ_A(c, 0);
        READ_B(c, 0);
        PHASE_BAR1();
        MFMA8(0, 0);
        asm volatile("s_waitcnt vmcnt(1)" ::: "memory");  // B1 landed
        __builtin_amdgcn_s_barrier();

        READ_B(c, 1);
        PHASE_BAR1();
        MFMA8(0, 1);
        asm volatile("s_waitcnt vmcnt(0)" ::: "memory");  // A1 landed
        __builtin_amdgcn_s_barrier();

        READ_A(c, 1);
        PHASE_BAR1();
        MFMA8(1, 1);
        __builtin_amdgcn_s_barrier();

        READ_B(c, 0);
        PHASE_BAR1();
        MFMA8(1, 0);
    }

    // epilogue: fp32 bias + store (same numerics/layouts as previous kernel)
#pragma unroll
    for (int an = 0; an < 4; ++an) {
        const int col = n0 + ((w & 3) << 5) + (an >> 1) * 128 +
                        (an & 1) * 16 + l15;
        float bias;
        if (mode == 0)      bias = bq[col];
        else if (mode == 1) bias = bk[col] + 0.2f * bbar[col] + 0.1f * bbeat[col];
        else                bias = bv[col];
#pragma unroll
        for (int am = 0; am < 4; ++am) {
            const int rowbase = m0 + ((w >> 2) << 5) + (am >> 1) * 64 +
                                (am & 1) * 16 + quad * 4;
            if (mode == 2) {
                const int bb = rowbase >> 10;
                const int sb = rowbase & 1023;
                bf16x4 vv;
#pragma unroll
                for (int r = 0; r < 4; ++r) vv[r] = (__bf16)(acc[am][an][r] + bias);
                *(bf16x4*)&vtbuf[((size_t)(bb * 1024 + col)) * 1024 + sb] = vv;
            } else if (mode == 0) {
#pragma unroll
                for (int r = 0; r < 4; ++r)
                    qbuf[(size_t)(rowbase + r) * DMODEL + col] =
                        (__bf16)((acc[am][an][r] + bias) * 0.125f);  // attn scale
            } else {
#pragma unroll
                for (int r = 0; r < 4; ++r)
                    keffbuf[(size_t)(rowbase + r) * DMODEL + col] =
                        (__bf16)(acc[am][an][r] + bias);
            }
        }
    }
}

// ---------------------------------------------------------------------------
// out-proj: out = attn @ Wo^T + bo (fp32). 64x128 tile, grid 512 (2/CU).
// Wave tile 32x64: 2x4 fragments. m97 staging. (unchanged this round)
// ---------------------------------------------------------------------------
__global__ __launch_bounds__(256) void oproj_kernel(
    const __bf16* __restrict__ attnb, const __bf16* __restrict__ Wob,
    const float* __restrict__ bo, float* __restrict__ outb)
{
    const int tile = blockIdx.x;          // 512 = 64 (m) x 8 (n)
    const int m0 = (tile >> 3) << 6;
    const int n0 = (tile & 7) << 7;

    __shared__ __align__(16) __bf16 Alds[64 * 32];
    __shared__ __align__(16) __bf16 Blds[128 * 32];

    const int t    = threadIdx.x;
    const int w    = t >> 6;
    const int lane = t & 63;
    const int l15  = lane & 15;
    const int quad = lane >> 4;
    const int wm   = (w >> 1) << 5;   // 2 m-waves x 2 n-waves
    const int wn   = (w & 1) << 6;
    const int srow = t >> 2;
    const int scol = (t & 3) * 8;

    const __bf16* gA  = attnb + (size_t)(m0 + srow) * DMODEL + scol;
    const __bf16* gB0 = Wob + (size_t)(n0 + srow) * DMODEL + scol;
    const __bf16* gB1 = Wob + (size_t)(n0 + 64 + srow) * DMODEL + scol;
    __bf16* lA  = &Alds[w * 512];
    __bf16* lB0 = &Blds[w * 512];
    __bf16* lB1 = &Blds[2048 + w * 512];

    f32x4 acc[2][4];
    for (int i = 0; i < 2; ++i)
        for (int j = 0; j < 4; ++j)
            acc[i][j] = {0.f, 0.f, 0.f, 0.f};

    for (int kk = 0; kk < 32; ++kk) {
        const int k0 = kk * 32;
        ASYNC_LOAD16(gA + k0, lA);
        ASYNC_LOAD16(gB0 + k0, lB0);
        ASYNC_LOAD16(gB1 + k0, lB1);
        __syncthreads();

        bf16x8 af[2], bfr[4];
        for (int i = 0; i < 2; ++i)
            af[i] = *(const bf16x8*)&Alds[(wm + i * 16 + l15) * 32 + quad * 8];
        for (int j = 0; j < 4; ++j)
            bfr[j] = *(const bf16x8*)&Blds[(wn + j * 16 + l15) * 32 + quad * 8];

        for (int i = 0; i < 2; ++i)
            for (int j = 0; j < 4; ++j)
                acc[i][j] = __builtin_amdgcn_mfma_f32_16x16x32_bf16(
                    af[i], bfr[j], acc[i][j], 0, 0, 0);
        __syncthreads();
    }

    for (int j = 0; j < 4; ++j) {
        const int col = n0 + wn + j * 16 + l15;
        const float bias = bo[col];
        for (int i = 0; i < 2; ++i) {
            const int rowbase = m0 + wm + i * 16 + quad * 4;
            for (int r = 0; r < 4; ++r)
                outb[(size_t)(rowbase + r) * DMODEL + col] = acc[i][j][r] + bias;
        }
    }
}

// ---------------------------------------------------------------------------
// flash attention: one block per (b, h, 64 q-rows). causal. q pre-scaled by
// 0.125. Shift-free softmax (bounded scores), rowsum via ones-MFMA.
// (unchanged this round)
// ---------------------------------------------------------------------------
__global__ __launch_bounds__(256) void attn_kernel(
    const __bf16* __restrict__ qbuf, const __bf16* __restrict__ keffbuf,
    const __bf16* __restrict__ vtbuf, __bf16* __restrict__ attnbuf)
{
    const int bh = blockIdx.y;
    const int b  = bh >> 4;
    const int h  = bh & 15;
    const int qt = blockIdx.x;
    const int q0 = qt * 64;

    __shared__ __align__(16) __bf16 Klds[64][72];
    __shared__ __align__(16) __bf16 Vlds[64][72];
    __shared__ __align__(16) __bf16 Plds[4][16][72];

    const int t    = threadIdx.x;
    const int w    = t >> 6;
    const int lane = t & 63;
    const int l15  = lane & 15;
    const int quad = lane >> 4;

    const __bf16* qbase =
        qbuf + (size_t)(b * 1024 + q0 + w * 16 + l15) * DMODEL + h * 64;
    bf16x8 qf0 = *(const bf16x8*)&qbase[quad * 8];
    bf16x8 qf1 = *(const bf16x8*)&qbase[32 + quad * 8];

    bf16x8 ones;
    for (int i = 0; i < 8; ++i) ones[i] = (__bf16)1.0f;

    f32x4 o[4];
    for (int i = 0; i < 4; ++i) o[i] = {0.f, 0.f, 0.f, 0.f};
    f32x4 lacc = {0.f, 0.f, 0.f, 0.f};

    const int srow = t >> 2;
    const int scol = (t & 3) * 16;

    const __bf16* kbase = keffbuf + (size_t)(b * 1024) * DMODEL + h * 64;
    const __bf16* vtb   = vtbuf + (size_t)(b * 1024 + h * 64) * 1024;

    for (int j = 0; j <= qt; ++j) {
        const __bf16* kg = kbase + (size_t)(j * 64 + srow) * DMODEL + scol;
        *(bf16x8*)&Klds[srow][scol]     = *(const bf16x8*)kg;
        *(bf16x8*)&Klds[srow][scol + 8] = *(const bf16x8*)(kg + 8);
        const __bf16* vg = vtb + (size_t)srow * 1024 + j * 64 + scol;
        *(bf16x8*)&Vlds[srow][scol]     = *(const bf16x8*)vg;
        *(bf16x8*)&Vlds[srow][scol + 8] = *(const bf16x8*)(vg + 8);
        __syncthreads();

        f32x4 sc[4];
        for (int nt = 0; nt < 4; ++nt) {
            sc[nt] = {0.f, 0.f, 0.f, 0.f};
            bf16x8 kf0 = *(const bf16x8*)&Klds[nt * 16 + l15][quad * 8];
            bf16x8 kf1 = *(const bf16x8*)&Klds[nt * 16 + l15][32 + quad * 8];
            sc[nt] = __builtin_amdgcn_mfma_f32_16x16x32_bf16(qf0, kf0, sc[nt], 0, 0, 0);
            sc[nt] = __builtin_amdgcn_mfma_f32_16x16x32_bf16(qf1, kf1, sc[nt], 0, 0, 0);
        }

        // causal mask (diagonal tile only): -1e30 -> exp underflows to 0
        if (j == qt) {
            const int qrow_base = q0 + w * 16 + quad * 4;
            for (int nt = 0; nt < 4; ++nt) {
                const int kcol = j * 64 + nt * 16 + l15;
                for (int r = 0; r < 4; ++r)
                    if (kcol > qrow_base + r) sc[nt][r] = -1e30f;
            }
        }

        // shift-free exp
        for (int nt = 0; nt < 4; ++nt)
            for (int r = 0; r < 4; ++r)
                sc[nt][r] = __expf(sc[nt][r]);

        // P -> per-wave LDS (C-layout), read back as A-layout frags
        for (int nt = 0; nt < 4; ++nt)
            for (int r = 0; r < 4; ++r)
                Plds[w][quad * 4 + r][nt * 16 + l15] = (__bf16)sc[nt][r];
        asm volatile("s_waitcnt lgkmcnt(0)" ::: "memory");

        bf16x8 pf0 = *(const bf16x8*)&Plds[w][l15][quad * 8];
        bf16x8 pf1 = *(const bf16x8*)&Plds[w][l15][32 + quad * 8];

        // row-sum via ones-MFMA (replicated over lanes, no shuffles)
        lacc = __builtin_amdgcn_mfma_f32_16x16x32_bf16(pf0, ones, lacc, 0, 0, 0);
        lacc = __builtin_amdgcn_mfma_f32_16x16x32_bf16(pf1, ones, lacc, 0, 0, 0);

        for (int nd = 0; nd < 4; ++nd) {
            bf16x8 vf0 = *(const bf16x8*)&Vlds[nd * 16 + l15][quad * 8];
            bf16x8 vf1 = *(const bf16x8*)&Vlds[nd * 16 + l15][32 + quad * 8];
            o[nd] = __builtin_amdgcn_mfma_f32_16x16x32_bf16(pf0, vf0, o[nd], 0, 0, 0);
            o[nd] = __builtin_amdgcn_mfma_f32_16x16x32_bf16(pf1, vf1, o[nd], 0, 0, 0);
        }
        __syncthreads();
    }

    float rinv[4];
    for (int r = 0; r < 4; ++r) rinv[r] = 1.0f / lacc[r];
    for (int nd = 0; nd < 4; ++nd) {
        for (int r = 0; r < 4; ++r) {
            const int row = q0 + w * 16 + quad * 4 + r;
            attnbuf[(size_t)(b * 1024 + row) * DMODEL + h * 64 + nd * 16 + l15] =
                (__bf16)(o[nd][r] * rinv[r]);
        }
    }
}

extern "C" void kernel_launch(void* const* d_in, const int* in_sizes, int n_in,
                              void* d_out, int out_size, void* d_ws, size_t ws_size,
                              hipStream_t stream) {
    const float* x     = (const float*)d_in[0];
    const int* bar     = (const int*)d_in[2];
    const int* beat    = (const int*)d_in[3];
    const float* Wq    = (const float*)d_in[4];
    const float* bq    = (const float*)d_in[5];
    const float* Wk    = (const float*)d_in[6];
    const float* bk    = (const float*)d_in[7];
    const float* Wv    = (const float*)d_in[8];
    const float* bv    = (const float*)d_in[9];
    const float* Wbar  = (const float*)d_in[10];
    const float* bbar  = (const float*)d_in[11];
    const float* Wbeat = (const float*)d_in[12];
    const float* bbeat = (const float*)d_in[13];
    const float* Wo    = (const float*)d_in[14];
    const float* bo    = (const float*)d_in[15];

    const size_t M1 = (size_t)1 << 20;
    __bf16* xb     = (__bf16*)d_ws;       // 4M
    __bf16* Wqb    = xb + 4 * M1;         // 6 x 1M weights
    __bf16* Wkb    = Wqb + M1;
    __bf16* Wvb    = Wkb + M1;
    __bf16* Wbarb  = Wvb + M1;
    __bf16* Wbeatb = Wbarb + M1;
    __bf16* Wob    = Wbeatb + M1;
    __bf16* qbuf   = Wob + M1;            // 4M
    __bf16* keff   = qbuf + 4 * M1;       // 4M
    __bf16* vt     = keff + 4 * M1;       // 4M
    __bf16* attn   = vt + 4 * M1;         // 4M
    float*  outb   = (float*)d_out;

    cvt_kernel<<<5120, 256, 0, stream>>>(x, Wq, Wk, Wv, Wbar, Wbeat, Wo, xb);

    gemm8p_kernel<<<384, 512, 0, stream>>>(
        xb, Wqb, Wkb, Wvb, Wbarb, Wbeatb,
        bq, bk, bv, bbar, bbeat, bar, beat,
        qbuf, keff, vt);

    attn_kernel<<<dim3(16, 64), 256, 0, stream>>>(qbuf, keff, vt, attn);

    oproj_kernel<<<512, 256, 0, stream>>>(attn, Wob, bo, outb);
}

// Round 2
// 241.793 us; speedup vs baseline: 1.0125x; 1.0125x over previous
//
#include <hip/hip_runtime.h>
#include <hip/hip_bf16.h>

// B=4, S=1024, D=1024, H=16, HD=64 — tokens M=4096, feature K=1024
// fp32 inputs -> bf16 convert pass -> all GEMMs/attention in bf16 MFMA
// (fp32 accumulate) -> fp32 output.
// ROUND 2: fix the T2 swizzle. Round-1's 1-bit XOR ((row>>2)&1 -> bit5)
// spread each quarter-wave's 16 rows over only 2 of 8 slots -> still 8-way
// conflicts (counter went UP to 6.5M). Correct recipe for "lanes read
// different ROWS at same col-slot of 128B rows": byte ^= ((row&7)<<4)
// (3 bits, 8 slots, 2 rows/slot = free; §6 G4 / m214 r268). Applied
// both-sides: linear gload_lds dest + XOR'd global SOURCE col + XOR'd
// ds_read col. Same 2-bit fix ((row&3)<<4) for oproj's 64B rows.
// Schedule/vmcnt structure unchanged from round 1 (audited correct).

typedef __bf16 bf16x8 __attribute__((ext_vector_type(8)));
typedef __bf16 bf16x4 __attribute__((ext_vector_type(4)));
typedef float  f32x4  __attribute__((ext_vector_type(4)));

#define DMODEL 1024

#define ASYNC_LOAD16(gp, lp)                                                  \
    __builtin_amdgcn_global_load_lds(                                         \
        (const __attribute__((address_space(1))) unsigned int*)(gp),          \
        (__attribute__((address_space(3))) unsigned int*)(lp), 16, 0, 0)

// ---------------------------------------------------------------------------
// fp32 -> bf16 conversion: x (4M) + 6 weights (1M each); Wbar pre-scaled by
// 0.2 and Wbeat by 0.1 (folds the score-bias scales into the GEMM).
// ---------------------------------------------------------------------------
__global__ __launch_bounds__(256) void cvt_kernel(
    const float* __restrict__ x,
    const float* __restrict__ Wq, const float* __restrict__ Wk,
    const float* __restrict__ Wv, const float* __restrict__ Wbar,
    const float* __restrict__ Wbeat, const float* __restrict__ Wo,
    __bf16* __restrict__ dst)
{
    const int g = blockIdx.x * 256 + threadIdx.x;
    const size_t e = (size_t)g * 8;
    const int seg = (int)(e >> 20);
    const float* src; size_t off; float s = 1.0f;
    if (seg < 4)       { src = x;     off = e; }
    else if (seg == 4) { src = Wq;    off = e - ((size_t)4 << 20); }
    else if (seg == 5) { src = Wk;    off = e - ((size_t)5 << 20); }
    else if (seg == 6) { src = Wv;    off = e - ((size_t)6 << 20); }
    else if (seg == 7) { src = Wbar;  off = e - ((size_t)7 << 20); s = 0.2f; }
    else if (seg == 8) { src = Wbeat; off = e - ((size_t)8 << 20); s = 0.1f; }
    else               { src = Wo;    off = e - ((size_t)9 << 20); }
    const float4 a = *(const float4*)&src[off];
    const float4 b = *(const float4*)&src[off + 4];
    bf16x8 v;
    v[0] = (__bf16)(a.x * s); v[1] = (__bf16)(a.y * s);
    v[2] = (__bf16)(a.z * s); v[3] = (__bf16)(a.w * s);
    v[4] = (__bf16)(b.x * s); v[5] = (__bf16)(b.y * s);
    v[6] = (__bf16)(b.z * s); v[7] = (__bf16)(b.w * s);
    *(bf16x8*)&dst[e] = v;
}

// ---------------------------------------------------------------------------
// 8-phase GEMM: BM=128, BN=256, BK=64, 512 threads = 8 waves (2M x 4N),
// wave tile 64x64. LDS: A 2x[128][64] + B 2x[256][64] = 96KB, linear layout
// for global_load_lds. Swizzle (T2, both-sides): byte col ^= ((row&7)<<4)
// — applied to the global SOURCE col at stage time and to the ds_read col.
// Per K-tile: 4 phases = C-quadrants; counted vmcnt, never 0 in main loop.
// Block map: bid 0..127 keff (3 terms, ONE fp32 acc over 48 K-tiles),
// 128..255 q (bias + 0.125 scale), 256..383 v (transposed store).
// ---------------------------------------------------------------------------

// read-side swizzled col (elements): rows are always ...*16 + l15 so
// row&7 == l15&7; byte col = (ks*64 + quad*16) ^ ((l15&7)<<4)
#define SWZ_COL(r_, ks_) \
    (((((ks_) * 64) + quad * 16) ^ (((r_) & 7) << 4)) >> 1)

#define READ_A(c_, mh_)                                                       \
    do {                                                                      \
        _Pragma("unroll") for (int mi = 0; mi < 2; ++mi) {                    \
            const int r_ = ((w >> 2) << 5) + (mh_) * 64 + mi * 16 + l15;      \
            _Pragma("unroll") for (int ks = 0; ks < 2; ++ks)                  \
                af[mi][ks] = *(const bf16x8*)&Alds[(c_) * 8192 + r_ * 64 +    \
                                                   SWZ_COL(r_, ks)];          \
        }                                                                     \
    } while (0)

#define READ_B(c_, nh_)                                                       \
    do {                                                                      \
        _Pragma("unroll") for (int nj = 0; nj < 2; ++nj) {                    \
            const int r_ = ((w & 3) << 5) + (nh_) * 128 + nj * 16 + l15;      \
            _Pragma("unroll") for (int ks = 0; ks < 2; ++ks)                  \
                bf[nj][ks] = *(const bf16x8*)&Blds[(c_) * 16384 + r_ * 64 +   \
                                                    SWZ_COL(r_, ks)];         \
        }                                                                     \
    } while (0)

#define STAGE_A8(bufn_, h_, kt_)                                              \
    do {                                                                      \
        const int tm_ = (kt_) >> 4;                                           \
        const int k0_ = ((kt_) & 15) << 6;                                    \
        const __bf16* ap_ = (tm_ == 0) ? aA0##h_ : (tm_ == 1) ? aA1##h_       \
                                                              : aA2##h_;      \
        ASYNC_LOAD16(ap_ + k0_,                                               \
                     &Alds[(bufn_) * 8192 + (h_) * 4096 + w * 512]);          \
    } while (0)

#define STAGE_B8(bufn_, h_, kt_)                                              \
    do {                                                                      \
        const int tm_ = (kt_) >> 4;                                           \
        const int k0_ = ((kt_) & 15) << 6;                                    \
        const __bf16* wp_ = (tm_ == 0) ? W0 : (tm_ == 1) ? W1 : W2;           \
        ASYNC_LOAD16(wp_ + bro##h_##0 + k0_,                                  \
                     &Blds[(bufn_) * 16384 + (h_) * 8192 + w * 512]);         \
        ASYNC_LOAD16(wp_ + bro##h_##1 + k0_,                                  \
                     &Blds[(bufn_) * 16384 + (h_) * 8192 + 4096 + w * 512]);  \
    } while (0)

#define PHASE_BAR1()                                                          \
    do {                                                                      \
        __builtin_amdgcn_s_barrier();                                         \
        asm volatile("s_waitcnt lgkmcnt(0)" ::: "memory");                    \
    } while (0)

#define MFMA8(mh_, nh_)                                                       \
    do {                                                                      \
        __builtin_amdgcn_s_setprio(1);                                        \
        _Pragma("unroll") for (int mi = 0; mi < 2; ++mi)                      \
        _Pragma("unroll") for (int nj = 0; nj < 2; ++nj) {                    \
            acc[(mh_)*2 + mi][(nh_)*2 + nj] =                                 \
                __builtin_amdgcn_mfma_f32_16x16x32_bf16(                      \
                    af[mi][0], bf[nj][0], acc[(mh_)*2 + mi][(nh_)*2 + nj],    \
                    0, 0, 0);                                                 \
            acc[(mh_)*2 + mi][(nh_)*2 + nj] =                                 \
                __builtin_amdgcn_mfma_f32_16x16x32_bf16(                      \
                    af[mi][1], bf[nj][1], acc[(mh_)*2 + mi][(nh_)*2 + nj],    \
                    0, 0, 0);                                                 \
        }                                                                     \
        __builtin_amdgcn_s_setprio(0);                                        \
    } while (0)

__global__ __launch_bounds__(512, 2) void gemm8p_kernel(
    const __bf16* __restrict__ xb,
    const __bf16* __restrict__ Wqb, const __bf16* __restrict__ Wkb,
    const __bf16* __restrict__ Wvb, const __bf16* __restrict__ Wbarb,
    const __bf16* __restrict__ Wbeatb,
    const float* __restrict__ bq, const float* __restrict__ bk,
    const float* __restrict__ bv, const float* __restrict__ bbar,
    const float* __restrict__ bbeat,
    const int* __restrict__ bar_idx, const int* __restrict__ beat_idx,
    __bf16* __restrict__ qbuf, __bf16* __restrict__ keffbuf,
    __bf16* __restrict__ vtbuf)
{
    __shared__ __align__(16) __bf16 Alds[2 * 8192];    // 2 buf x [128][64]
    __shared__ __align__(16) __bf16 Blds[2 * 16384];   // 2 buf x [256][64]

    const int bid = blockIdx.x;
    int mode, tk;
    if (bid < 128)      { mode = 1; tk = bid; }        // keff first (3x work)
    else if (bid < 256) { mode = 0; tk = bid - 128; }  // q
    else                { mode = 2; tk = bid - 256; }  // v
    const int m0 = (tk >> 2) << 7;                     // 32 m-tiles x 128
    const int n0 = (tk & 3) << 8;                      // 4 n-tiles x 256
    const int nkt = (mode == 1) ? 48 : 16;

    const int t    = (int)threadIdx.x;
    const int w    = t >> 6;
    const int lane = t & 63;
    const int l15  = lane & 15;
    const int quad = lane >> 4;

    // staging geometry: thread t stages 16B at linear LDS byte t*16 within
    // the half-tile block => row = t>>3, slot = t&7. Source col carries the
    // inverse (== same, involution) swizzle: byte ^= ((row&7)<<4).
    const int srow = t >> 3;                                    // 0..63
    const int scol = ((((t & 7) * 16) ^ (((t >> 3) & 7) << 4)) >> 1);

    const __bf16* aA00 = xb + (size_t)(m0 + srow) * DMODEL + scol;
    const __bf16* aA01 = xb + (size_t)(m0 + 64 + srow) * DMODEL + scol;
    const __bf16* aA10 = aA00; const __bf16* aA11 = aA01;
    const __bf16* aA20 = aA00; const __bf16* aA21 = aA01;
    const __bf16 *W0, *W1, *W2;
    if (mode == 0)      { W0 = W1 = W2 = Wqb; }
    else if (mode == 2) { W0 = W1 = W2 = Wvb; }
    else {
        W0 = Wkb; W1 = Wbarb; W2 = Wbeatb;
        const int bb = m0 & ~1023;                 // batch base row
        const int lr = m0 & 1023;                  // seq-local tile base
        aA10 = xb + (size_t)(bb + bar_idx[lr + srow]) * DMODEL + scol;
        aA11 = xb + (size_t)(bb + bar_idx[lr + 64 + srow]) * DMODEL + scol;
        aA20 = xb + (size_t)(bb + beat_idx[lr + srow]) * DMODEL + scol;
        aA21 = xb + (size_t)(bb + beat_idx[lr + 64 + srow]) * DMODEL + scol;
    }
    const size_t bro00 = (size_t)(n0 + srow) * DMODEL + scol;
    const size_t bro01 = (size_t)(n0 + 64 + srow) * DMODEL + scol;
    const size_t bro10 = (size_t)(n0 + 128 + srow) * DMODEL + scol;
    const size_t bro11 = (size_t)(n0 + 192 + srow) * DMODEL + scol;

    f32x4 acc[4][4];
#pragma unroll
    for (int i = 0; i < 4; ++i)
#pragma unroll
        for (int j = 0; j < 4; ++j)
            acc[i][j] = {0.f, 0.f, 0.f, 0.f};
    bf16x8 af[2][2], bf[2][2];

    // prologue: stage tile 0 in issue order [A0, B0x2, B1x2, A1]; publish
    // A0/B0 (oldest 3) and enter steady state with [B1x2, A1] in flight.
    STAGE_A8(0, 0, 0);
    asm volatile("" ::: "memory");
    STAGE_B8(0, 0, 0);
    asm volatile("" ::: "memory");
    STAGE_B8(0, 1, 0);
    asm volatile("" ::: "memory");
    STAGE_A8(0, 1, 0);
    asm volatile("s_waitcnt vmcnt(3)" ::: "memory");
    __builtin_amdgcn_s_barrier();

#pragma unroll 1
    for (int kt = 0; kt < nkt - 1; ++kt) {
        const int c  = kt & 1;
        const int nb = c ^ 1;
        const int kn = kt + 1;

        // ph0: quadrant (0,0) — reads A0,B0(t); stages A0(t+1)
        READ_A(c, 0);
        READ_B(c, 0);
        STAGE_A8(nb, 0, kn);
        PHASE_BAR1();
        MFMA8(0, 0);
        asm volatile("s_waitcnt vmcnt(2)" ::: "memory");  // B1(t) landed
        __builtin_amdgcn_s_barrier();

        // ph1: quadrant (0,1) — reads B1(t); stages B0(t+1)
        READ_B(c, 1);
        STAGE_B8(nb, 0, kn);
        PHASE_BAR1();
        MFMA8(0, 1);
        asm volatile("s_waitcnt vmcnt(3)" ::: "memory");  // A1(t) landed
        __builtin_amdgcn_s_barrier();

        // ph2: quadrant (1,1) — reads A1(t); stages B1(t+1)
        READ_A(c, 1);
        STAGE_B8(nb, 1, kn);
        PHASE_BAR1();
        MFMA8(1, 1);
        __builtin_amdgcn_s_barrier();                     // no wait needed

        // ph3: quadrant (1,0) — re-reads B0(t); stages A1(t+1)
        READ_B(c, 0);
        STAGE_A8(nb, 1, kn);
        PHASE_BAR1();
        MFMA8(1, 0);
        asm volatile("s_waitcnt vmcnt(3)" ::: "memory");  // A0,B0(t+1) landed
        __builtin_amdgcn_s_barrier();
    }

    // last tile (no staging): drain waits 1 -> 0
    {
        const int c = (nkt - 1) & 1;   // always 1 (nkt = 16 or 48)
        READ_A(c, 0);
        READ_B(c, 0);
        PHASE_BAR1();
        MFMA8(0, 0);
        asm volatile("s_waitcnt vmcnt(1)" ::: "memory");  // B1 landed
        __builtin_amdgcn_s_barrier();

        READ_B(c, 1);
        PHASE_BAR1();
        MFMA8(0, 1);
        asm volatile("s_waitcnt vmcnt(0)" ::: "memory");  // A1 landed
        __builtin_amdgcn_s_barrier();

        READ_A(c, 1);
        PHASE_BAR1();
        MFMA8(1, 1);
        __builtin_amdgcn_s_barrier();

        READ_B(c, 0);
        PHASE_BAR1();
        MFMA8(1, 0);
    }

    // epilogue: fp32 bias + store (same numerics/layouts as before)
#pragma unroll
    for (int an = 0; an < 4; ++an) {
        const int col = n0 + ((w & 3) << 5) + (an >> 1) * 128 +
                        (an & 1) * 16 + l15;
        float bias;
        if (mode == 0)      bias = bq[col];
        else if (mode == 1) bias = bk[col] + 0.2f * bbar[col] + 0.1f * bbeat[col];
        else                bias = bv[col];
#pragma unroll
        for (int am = 0; am < 4; ++am) {
            const int rowbase = m0 + ((w >> 2) << 5) + (am >> 1) * 64 +
                                (am & 1) * 16 + quad * 4;
            if (mode == 2) {
                const int bb = rowbase >> 10;
                const int sb = rowbase & 1023;
                bf16x4 vv;
#pragma unroll
                for (int r = 0; r < 4; ++r) vv[r] = (__bf16)(acc[am][an][r] + bias);
                *(bf16x4*)&vtbuf[((size_t)(bb * 1024 + col)) * 1024 + sb] = vv;
            } else if (mode == 0) {
#pragma unroll
                for (int r = 0; r < 4; ++r)
                    qbuf[(size_t)(rowbase + r) * DMODEL + col] =
                        (__bf16)((acc[am][an][r] + bias) * 0.125f);  // attn scale
            } else {
#pragma unroll
                for (int r = 0; r < 4; ++r)
                    keffbuf[(size_t)(rowbase + r) * DMODEL + col] =
                        (__bf16)(acc[am][an][r] + bias);
            }
        }
    }
}

// ---------------------------------------------------------------------------
// out-proj: out = attn @ Wo^T + bo (fp32). 64x128 tile, grid 512 (2/CU).
// Wave tile 32x64: 2x4 fragments. m97 staging + 2-bit T2 swizzle
// (64B rows = 4 slots: byte ^= ((row&3)<<4), 16-way -> 4-way conflicts).
// ---------------------------------------------------------------------------
__global__ __launch_bounds__(256) void oproj_kernel(
    const __bf16* __restrict__ attnb, const __bf16* __restrict__ Wob,
    const float* __restrict__ bo, float* __restrict__ outb)
{
    const int tile = blockIdx.x;          // 512 = 64 (m) x 8 (n)
    const int m0 = (tile >> 3) << 6;
    const int n0 = (tile & 7) << 7;

    __shared__ __align__(16) __bf16 Alds[64 * 32];
    __shared__ __align__(16) __bf16 Blds[128 * 32];

    const int t    = threadIdx.x;
    const int w    = t >> 6;
    const int lane = t & 63;
    const int l15  = lane & 15;
    const int quad = lane >> 4;
    const int wm   = (w >> 1) << 5;   // 2 m-waves x 2 n-waves
    const int wn   = (w & 1) << 6;
    const int srow = t >> 2;
    // source col swizzle: byte = (t&3)*16 ^ ((srow&3)<<4)
    const int scol = ((((t & 3) * 16) ^ (((t >> 2) & 3) << 4)) >> 1);
    // read col swizzle: rows are ...*16 + l15 -> row&3 == l15&3
    const int rcol = (((quad * 16) ^ ((l15 & 3) << 4)) >> 1);

    const __bf16* gA  = attnb + (size_t)(m0 + srow) * DMODEL + scol;
    const __bf16* gB0 = Wob + (size_t)(n0 + srow) * DMODEL + scol;
    const __bf16* gB1 = Wob + (size_t)(n0 + 64 + srow) * DMODEL + scol;
    __bf16* lA  = &Alds[w * 512];
    __bf16* lB0 = &Blds[w * 512];
    __bf16* lB1 = &Blds[2048 + w * 512];

    f32x4 acc[2][4];
    for (int i = 0; i < 2; ++i)
        for (int j = 0; j < 4; ++j)
            acc[i][j] = {0.f, 0.f, 0.f, 0.f};

    for (int kk = 0; kk < 32; ++kk) {
        const int k0 = kk * 32;
        ASYNC_LOAD16(gA + k0, lA);
        ASYNC_LOAD16(gB0 + k0, lB0);
        ASYNC_LOAD16(gB1 + k0, lB1);
        __syncthreads();

        bf16x8 af[2], bfr[4];
        for (int i = 0; i < 2; ++i)
            af[i] = *(const bf16x8*)&Alds[(wm + i * 16 + l15) * 32 + rcol];
        for (int j = 0; j < 4; ++j)
            bfr[j] = *(const bf16x8*)&Blds[(wn + j * 16 + l15) * 32 + rcol];

        for (int i = 0; i < 2; ++i)
            for (int j = 0; j < 4; ++j)
                acc[i][j] = __builtin_amdgcn_mfma_f32_16x16x32_bf16(
                    af[i], bfr[j], acc[i][j], 0, 0, 0);
        __syncthreads();
    }

    for (int j = 0; j < 4; ++j) {
        const int col = n0 + wn + j * 16 + l15;
        const float bias = bo[col];
        for (int i = 0; i < 2; ++i) {
            const int rowbase = m0 + wm + i * 16 + quad * 4;
            for (int r = 0; r < 4; ++r)
                outb[(size_t)(rowbase + r) * DMODEL + col] = acc[i][j][r] + bias;
        }
    }
}

// ---------------------------------------------------------------------------
// flash attention: one block per (b, h, 64 q-rows). causal. q pre-scaled by
// 0.125. Shift-free softmax (bounded scores), rowsum via ones-MFMA.
// [72]-padded LDS rows (144B stride) are already bank-spread — unchanged.
// ---------------------------------------------------------------------------
__global__ __launch_bounds__(256) void attn_kernel(
    const __bf16* __restrict__ qbuf, const __bf16* __restrict__ keffbuf,
    const __bf16* __restrict__ vtbuf, __bf16* __restrict__ attnbuf)
{
    const int bh = blockIdx.y;
    const int b  = bh >> 4;
    const int h  = bh & 15;
    const int qt = blockIdx.x;
    const int q0 = qt * 64;

    __shared__ __align__(16) __bf16 Klds[64][72];
    __shared__ __align__(16) __bf16 Vlds[64][72];
    __shared__ __align__(16) __bf16 Plds[4][16][72];

    const int t    = threadIdx.x;
    const int w    = t >> 6;
    const int lane = t & 63;
    const int l15  = lane & 15;
    const int quad = lane >> 4;

    const __bf16* qbase =
        qbuf + (size_t)(b * 1024 + q0 + w * 16 + l15) * DMODEL + h * 64;
    bf16x8 qf0 = *(const bf16x8*)&qbase[quad * 8];
    bf16x8 qf1 = *(const bf16x8*)&qbase[32 + quad * 8];

    bf16x8 ones;
    for (int i = 0; i < 8; ++i) ones[i] = (__bf16)1.0f;

    f32x4 o[4];
    for (int i = 0; i < 4; ++i) o[i] = {0.f, 0.f, 0.f, 0.f};
    f32x4 lacc = {0.f, 0.f, 0.f, 0.f};

    const int srow = t >> 2;
    const int scol = (t & 3) * 16;

    const __bf16* kbase = keffbuf + (size_t)(b * 1024) * DMODEL + h * 64;
    const __bf16* vtb   = vtbuf + (size_t)(b * 1024 + h * 64) * 1024;

    for (int j = 0; j <= qt; ++j) {
        const __bf16* kg = kbase + (size_t)(j * 64 + srow) * DMODEL + scol;
        *(bf16x8*)&Klds[srow][scol]     = *(const bf16x8*)kg;
        *(bf16x8*)&Klds[srow][scol + 8] = *(const bf16x8*)(kg + 8);
        const __bf16* vg = vtb + (size_t)srow * 1024 + j * 64 + scol;
        *(bf16x8*)&Vlds[srow][scol]     = *(const bf16x8*)vg;
        *(bf16x8*)&Vlds[srow][scol + 8] = *(const bf16x8*)(vg + 8);
        __syncthreads();

        f32x4 sc[4];
        for (int nt = 0; nt < 4; ++nt) {
            sc[nt] = {0.f, 0.f, 0.f, 0.f};
            bf16x8 kf0 = *(const bf16x8*)&Klds[nt * 16 + l15][quad * 8];
            bf16x8 kf1 = *(const bf16x8*)&Klds[nt * 16 + l15][32 + quad * 8];
            sc[nt] = __builtin_amdgcn_mfma_f32_16x16x32_bf16(qf0, kf0, sc[nt], 0, 0, 0);
            sc[nt] = __builtin_amdgcn_mfma_f32_16x16x32_bf16(qf1, kf1, sc[nt], 0, 0, 0);
        }

        // causal mask (diagonal tile only): -1e30 -> exp underflows to 0
        if (j == qt) {
            const int qrow_base = q0 + w * 16 + quad * 4;
            for (int nt = 0; nt < 4; ++nt) {
                const int kcol = j * 64 + nt * 16 + l15;
                for (int r = 0; r < 4; ++r)
                    if (kcol > qrow_base + r) sc[nt][r] = -1e30f;
            }
        }

        // shift-free exp
        for (int nt = 0; nt < 4; ++nt)
            for (int r = 0; r < 4; ++r)
                sc[nt][r] = __expf(sc[nt][r]);

        // P -> per-wave LDS (C-layout), read back as A-layout frags
        for (int nt = 0; nt < 4; ++nt)
            for (int r = 0; r < 4; ++r)
                Plds[w][quad * 4 + r][nt * 16 + l15] = (__bf16)sc[nt][r];
        asm volatile("s_waitcnt lgkmcnt(0)" ::: "memory");

        bf16x8 pf0 = *(const bf16x8*)&Plds[w][l15][quad * 8];
        bf16x8 pf1 = *(const bf16x8*)&Plds[w][l15][32 + quad * 8];

        // row-sum via ones-MFMA (replicated over lanes, no shuffles)
        lacc = __builtin_amdgcn_mfma_f32_16x16x32_bf16(pf0, ones, lacc, 0, 0, 0);
        lacc = __builtin_amdgcn_mfma_f32_16x16x32_bf16(pf1, ones, lacc, 0, 0, 0);

        for (int nd = 0; nd < 4; ++nd) {
            bf16x8 vf0 = *(const bf16x8*)&Vlds[nd * 16 + l15][quad * 8];
            bf16x8 vf1 = *(const bf16x8*)&Vlds[nd * 16 + l15][32 + quad * 8];
            o[nd] = __builtin_amdgcn_mfma_f32_16x16x32_bf16(pf0, vf0, o[nd], 0, 0, 0);
            o[nd] = __builtin_amdgcn_mfma_f32_16x16x32_bf16(pf1, vf1, o[nd], 0, 0, 0);
        }
        __syncthreads();
    }

    float rinv[4];
    for (int r = 0; r < 4; ++r) rinv[r] = 1.0f / lacc[r];
    for (int nd = 0; nd < 4; ++nd) {
        for (int r = 0; r < 4; ++r) {
            const int row = q0 + w * 16 + quad * 4 + r;
            attnbuf[(size_t)(b * 1024 + row) * DMODEL + h * 64 + nd * 16 + l15] =
                (__bf16)(o[nd][r] * rinv[r]);
        }
    }
}

extern "C" void kernel_launch(void* const* d_in, const int* in_sizes, int n_in,
                              void* d_out, int out_size, void* d_ws, size_t ws_size,
                              hipStream_t stream) {
    const float* x     = (const float*)d_in[0];
    const int* bar     = (const int*)d_in[2];
    const int* beat    = (const int*)d_in[3];
    const float* Wq    = (const float*)d_in[4];
    const float* bq    = (const float*)d_in[5];
    const float* Wk    = (const float*)d_in[6];
    const float* bk    = (const float*)d_in[7];
    const float* Wv    = (const float*)d_in[8];
    const float* bv    = (const float*)d_in[9];
    const float* Wbar  = (const float*)d_in[10];
    const float* bbar  = (const float*)d_in[11];
    const float* Wbeat = (const float*)d_in[12];
    const float* bbeat = (const float*)d_in[13];
    const float* Wo    = (const float*)d_in[14];
    const float* bo    = (const float*)d_in[15];

    const size_t M1 = (size_t)1 << 20;
    __bf16* xb     = (__bf16*)d_ws;       // 4M
    __bf16* Wqb    = xb + 4 * M1;         // 6 x 1M weights
    __bf16* Wkb    = Wqb + M1;
    __bf16* Wvb    = Wkb + M1;
    __bf16* Wbarb  = Wvb + M1;
    __bf16* Wbeatb = Wbarb + M1;
    __bf16* Wob    = Wbeatb + M1;
    __bf16* qbuf   = Wob + M1;            // 4M
    __bf16* keff   = qbuf + 4 * M1;       // 4M
    __bf16* vt     = keff + 4 * M1;       // 4M
    __bf16* attn   = vt + 4 * M1;         // 4M
    float*  outb   = (float*)d_out;

    cvt_kernel<<<5120, 256, 0, stream>>>(x, Wq, Wk, Wv, Wbar, Wbeat, Wo, xb);

    gemm8p_kernel<<<384, 512, 0, stream>>>(
        xb, Wqb, Wkb, Wvb, Wbarb, Wbeatb,
        bq, bk, bv, bbar, bbeat, bar, beat,
        qbuf, keff, vt);

    attn_kernel<<<dim3(16, 64), 256, 0, stream>>>(qbuf, keff, vt, attn);

    oproj_kernel<<<512, 256, 0, stream>>>(attn, Wob, bo, outb);
}

// Round 3
// 221.498 us; speedup vs baseline: 1.1052x; 1.0916x over previous
//
#include <hip/hip_runtime.h>
#include <hip/hip_bf16.h>

// B=4, S=1024, D=1024, H=16, HD=64 — tokens M=4096, feature K=1024
// fp32 inputs -> bf16 convert pass -> all GEMMs/attention in bf16 MFMA
// (fp32 accumulate) -> fp32 output.
// ROUND 3: schedule restructure. R2 measured 936 cy/phase with only 310 cy
// of MFMA — overhead was 3 vmcnt waits/K-tile at ~1.5-phase issue-to-wait
// distance + 8 barriers/K-tile. New schedule: 2 phases per K-tile, 3-deep
// LDS buffer (144KB), ONE counted vmcnt(6) per K-tile with issue-to-wait
// distance of 2 FULL K-tiles, 2 barriers/K-tile, 16 MFMA per barrier-pair
// (m201-level amortization), 16 ds_reads/K-tile (B0 re-read eliminated).
// T2 swizzle unchanged (round-2 verified: 0 bank conflicts).

typedef __bf16 bf16x8 __attribute__((ext_vector_type(8)));
typedef __bf16 bf16x4 __attribute__((ext_vector_type(4)));
typedef float  f32x4  __attribute__((ext_vector_type(4)));

#define DMODEL 1024

#define ASYNC_LOAD16(gp, lp)                                                  \
    __builtin_amdgcn_global_load_lds(                                         \
        (const __attribute__((address_space(1))) unsigned int*)(gp),          \
        (__attribute__((address_space(3))) unsigned int*)(lp), 16, 0, 0)

// ---------------------------------------------------------------------------
// fp32 -> bf16 conversion: x (4M) + 6 weights (1M each); Wbar pre-scaled by
// 0.2 and Wbeat by 0.1 (folds the score-bias scales into the GEMM).
// ---------------------------------------------------------------------------
__global__ __launch_bounds__(256) void cvt_kernel(
    const float* __restrict__ x,
    const float* __restrict__ Wq, const float* __restrict__ Wk,
    const float* __restrict__ Wv, const float* __restrict__ Wbar,
    const float* __restrict__ Wbeat, const float* __restrict__ Wo,
    __bf16* __restrict__ dst)
{
    const int g = blockIdx.x * 256 + threadIdx.x;
    const size_t e = (size_t)g * 8;
    const int seg = (int)(e >> 20);
    const float* src; size_t off; float s = 1.0f;
    if (seg < 4)       { src = x;     off = e; }
    else if (seg == 4) { src = Wq;    off = e - ((size_t)4 << 20); }
    else if (seg == 5) { src = Wk;    off = e - ((size_t)5 << 20); }
    else if (seg == 6) { src = Wv;    off = e - ((size_t)6 << 20); }
    else if (seg == 7) { src = Wbar;  off = e - ((size_t)7 << 20); s = 0.2f; }
    else if (seg == 8) { src = Wbeat; off = e - ((size_t)8 << 20); s = 0.1f; }
    else               { src = Wo;    off = e - ((size_t)9 << 20); }
    const float4 a = *(const float4*)&src[off];
    const float4 b = *(const float4*)&src[off + 4];
    bf16x8 v;
    v[0] = (__bf16)(a.x * s); v[1] = (__bf16)(a.y * s);
    v[2] = (__bf16)(a.z * s); v[3] = (__bf16)(a.w * s);
    v[4] = (__bf16)(b.x * s); v[5] = (__bf16)(b.y * s);
    v[6] = (__bf16)(b.z * s); v[7] = (__bf16)(b.w * s);
    *(bf16x8*)&dst[e] = v;
}

// ---------------------------------------------------------------------------
// 2-phase / 3-buffer GEMM: BM=128, BN=256, BK=64, 512 threads = 8 waves
// (2M x 4N), wave tile 64x64 (acc 4x4). LDS: A 3x[128][64] + B 3x[256][64]
// = 144KB, linear layout for global_load_lds, T2 swizzle byte^=((row&7)<<4)
// on source + read (round-2 verified: 0 conflicts).
// Per K-tile t (read buf rc=t%3, stage buf fc=(t+2)%3):
//   phA: 16x ds_read_b128 (all frags); stage A(t+2) [2 loads]; barrier;
//        lgkmcnt(0); setprio; 16 MFMA (nh=0); setprio.
//   phB: stage B(t+2) [4 loads]; vmcnt(6) [t+1's 6 loads landed, t+2's 6
//        in flight — issue-to-wait = 2 K-tiles]; barrier; 16 MFMA (nh=1).
// Drain: vmcnt(0) at kt==nkt-2 only.
// Block map: bid 0..127 keff (3 terms, ONE fp32 acc over 48 K-tiles),
// 128..255 q (bias + 0.125 scale), 256..383 v (transposed store).
// ---------------------------------------------------------------------------

#define SWZ_COL(r_, ks_) \
    (((((ks_) * 64) + quad * 16) ^ (((r_) & 7) << 4)) >> 1)

#define READ_ALL(c_)                                                          \
    do {                                                                      \
        _Pragma("unroll") for (int mh = 0; mh < 2; ++mh)                      \
        _Pragma("unroll") for (int mi = 0; mi < 2; ++mi) {                    \
            const int r_ = ((w >> 2) << 5) + mh * 64 + mi * 16 + l15;         \
            _Pragma("unroll") for (int ks = 0; ks < 2; ++ks)                  \
                af[mh][mi][ks] = *(const bf16x8*)&Alds[(c_) * 8192 +          \
                                        r_ * 64 + SWZ_COL(r_, ks)];           \
        }                                                                     \
        _Pragma("unroll") for (int nh = 0; nh < 2; ++nh)                      \
        _Pragma("unroll") for (int nj = 0; nj < 2; ++nj) {                    \
            const int r_ = ((w & 3) << 5) + nh * 128 + nj * 16 + l15;         \
            _Pragma("unroll") for (int ks = 0; ks < 2; ++ks)                  \
                bfr[nh][nj][ks] = *(const bf16x8*)&Blds[(c_) * 16384 +        \
                                        r_ * 64 + SWZ_COL(r_, ks)];           \
        }                                                                     \
    } while (0)

#define STAGE_A1(bufn_, h_, kt_)                                              \
    do {                                                                      \
        const int tm_ = (kt_) >> 4;                                           \
        const int k0_ = ((kt_) & 15) << 6;                                    \
        const __bf16* ap_ = (tm_ == 0) ? aA0##h_ : (tm_ == 1) ? aA1##h_       \
                                                              : aA2##h_;      \
        ASYNC_LOAD16(ap_ + k0_,                                               \
                     &Alds[(bufn_) * 8192 + (h_) * 4096 + w * 512]);          \
    } while (0)

#define STAGE_B2(bufn_, h_, kt_)                                              \
    do {                                                                      \
        const int tm_ = (kt_) >> 4;                                           \
        const int k0_ = ((kt_) & 15) << 6;                                    \
        const __bf16* wp_ = (tm_ == 0) ? W0 : (tm_ == 1) ? W1 : W2;           \
        ASYNC_LOAD16(wp_ + bro##h_##0 + k0_,                                  \
                     &Blds[(bufn_) * 16384 + (h_) * 8192 + w * 512]);         \
        ASYNC_LOAD16(wp_ + bro##h_##1 + k0_,                                  \
                     &Blds[(bufn_) * 16384 + (h_) * 8192 + 4096 + w * 512]);  \
    } while (0)

#define PHASE_BAR1()                                                          \
    do {                                                                      \
        __builtin_amdgcn_s_barrier();                                         \
        asm volatile("s_waitcnt lgkmcnt(0)" ::: "memory");                    \
    } while (0)

#define MFMA16(nh_)                                                           \
    do {                                                                      \
        __builtin_amdgcn_s_setprio(1);                                        \
        _Pragma("unroll") for (int mh = 0; mh < 2; ++mh)                      \
        _Pragma("unroll") for (int mi = 0; mi < 2; ++mi)                      \
        _Pragma("unroll") for (int nj = 0; nj < 2; ++nj)                      \
        _Pragma("unroll") for (int ks = 0; ks < 2; ++ks) {                    \
            acc[mh * 2 + mi][(nh_) * 2 + nj] =                                \
                __builtin_amdgcn_mfma_f32_16x16x32_bf16(                      \
                    af[mh][mi][ks], bfr[(nh_)][nj][ks],                       \
                    acc[mh * 2 + mi][(nh_) * 2 + nj], 0, 0, 0);               \
        }                                                                     \
        __builtin_amdgcn_s_setprio(0);                                        \
    } while (0)

__global__ __launch_bounds__(512, 2) void gemm8p_kernel(
    const __bf16* __restrict__ xb,
    const __bf16* __restrict__ Wqb, const __bf16* __restrict__ Wkb,
    const __bf16* __restrict__ Wvb, const __bf16* __restrict__ Wbarb,
    const __bf16* __restrict__ Wbeatb,
    const float* __restrict__ bq, const float* __restrict__ bk,
    const float* __restrict__ bv, const float* __restrict__ bbar,
    const float* __restrict__ bbeat,
    const int* __restrict__ bar_idx, const int* __restrict__ beat_idx,
    __bf16* __restrict__ qbuf, __bf16* __restrict__ keffbuf,
    __bf16* __restrict__ vtbuf)
{
    __shared__ __align__(16) __bf16 Alds[3 * 8192];    // 3 buf x [128][64]
    __shared__ __align__(16) __bf16 Blds[3 * 16384];   // 3 buf x [256][64]

    const int bid = blockIdx.x;
    int mode, tk;
    if (bid < 128)      { mode = 1; tk = bid; }        // keff first (3x work)
    else if (bid < 256) { mode = 0; tk = bid - 128; }  // q
    else                { mode = 2; tk = bid - 256; }  // v
    const int m0 = (tk >> 2) << 7;                     // 32 m-tiles x 128
    const int n0 = (tk & 3) << 8;                      // 4 n-tiles x 256
    const int nkt = (mode == 1) ? 48 : 16;

    const int t    = (int)threadIdx.x;
    const int w    = t >> 6;
    const int lane = t & 63;
    const int l15  = lane & 15;
    const int quad = lane >> 4;

    // staging: thread t stages 16B at linear LDS byte t*16 within the
    // half-tile block => row = t>>3, slot = t&7. Source col carries the
    // involution swizzle: byte ^= ((row&7)<<4).
    const int srow = t >> 3;                                    // 0..63
    const int scol = ((((t & 7) * 16) ^ (((t >> 3) & 7) << 4)) >> 1);

    const __bf16* aA00 = xb + (size_t)(m0 + srow) * DMODEL + scol;
    const __bf16* aA01 = xb + (size_t)(m0 + 64 + srow) * DMODEL + scol;
    const __bf16* aA10 = aA00; const __bf16* aA11 = aA01;
    const __bf16* aA20 = aA00; const __bf16* aA21 = aA01;
    const __bf16 *W0, *W1, *W2;
    if (mode == 0)      { W0 = W1 = W2 = Wqb; }
    else if (mode == 2) { W0 = W1 = W2 = Wvb; }
    else {
        W0 = Wkb; W1 = Wbarb; W2 = Wbeatb;
        const int bb = m0 & ~1023;                 // batch base row
        const int lr = m0 & 1023;                  // seq-local tile base
        aA10 = xb + (size_t)(bb + bar_idx[lr + srow]) * DMODEL + scol;
        aA11 = xb + (size_t)(bb + bar_idx[lr + 64 + srow]) * DMODEL + scol;
        aA20 = xb + (size_t)(bb + beat_idx[lr + srow]) * DMODEL + scol;
        aA21 = xb + (size_t)(bb + beat_idx[lr + 64 + srow]) * DMODEL + scol;
    }
    const size_t bro00 = (size_t)(n0 + srow) * DMODEL + scol;
    const size_t bro01 = (size_t)(n0 + 64 + srow) * DMODEL + scol;
    const size_t bro10 = (size_t)(n0 + 128 + srow) * DMODEL + scol;
    const size_t bro11 = (size_t)(n0 + 192 + srow) * DMODEL + scol;

    f32x4 acc[4][4];
#pragma unroll
    for (int i = 0; i < 4; ++i)
#pragma unroll
        for (int j = 0; j < 4; ++j)
            acc[i][j] = {0.f, 0.f, 0.f, 0.f};
    bf16x8 af[2][2][2], bfr[2][2][2];

    // prologue: stage tiles 0 and 1 fully (6 loads each, issue order
    // A0,A1,B0,B1 per tile); wait tile 0 (vmcnt(6)), publish.
    STAGE_A1(0, 0, 0);
    STAGE_A1(0, 1, 0);
    STAGE_B2(0, 0, 0);
    STAGE_B2(0, 1, 0);
    asm volatile("" ::: "memory");
    STAGE_A1(1, 0, 1);
    STAGE_A1(1, 1, 1);
    STAGE_B2(1, 0, 1);
    STAGE_B2(1, 1, 1);
    asm volatile("s_waitcnt vmcnt(6)" ::: "memory");
    __builtin_amdgcn_s_barrier();

    int rc = 0, fc = 2;
#pragma unroll 1
    for (int kt = 0; kt < nkt; ++kt) {
        const int kn = kt + 2;
        const bool st = (kn < nkt);

        // phA: all ds_reads of tile kt; A-stage of kt+2
        READ_ALL(rc);
        if (st) { STAGE_A1(fc, 0, kn); STAGE_A1(fc, 1, kn); }
        PHASE_BAR1();
        MFMA16(0);

        // phB: B-stage of kt+2; single counted wait; publish tile kt+1
        if (st) { STAGE_B2(fc, 0, kn); STAGE_B2(fc, 1, kn); }
        if (kt < nkt - 2)
            asm volatile("s_waitcnt vmcnt(6)" ::: "memory");
        else if (kt == nkt - 2)
            asm volatile("s_waitcnt vmcnt(0)" ::: "memory");
        PHASE_BAR1();
        MFMA16(1);

        rc = (rc == 2) ? 0 : rc + 1;
        fc = (fc == 2) ? 0 : fc + 1;
    }

    // epilogue: fp32 bias + store (same numerics/layouts as before)
#pragma unroll
    for (int an = 0; an < 4; ++an) {
        const int col = n0 + ((w & 3) << 5) + (an >> 1) * 128 +
                        (an & 1) * 16 + l15;
        float bias;
        if (mode == 0)      bias = bq[col];
        else if (mode == 1) bias = bk[col] + 0.2f * bbar[col] + 0.1f * bbeat[col];
        else                bias = bv[col];
#pragma unroll
        for (int am = 0; am < 4; ++am) {
            const int rowbase = m0 + ((w >> 2) << 5) + (am >> 1) * 64 +
                                (am & 1) * 16 + quad * 4;
            if (mode == 2) {
                const int bb = rowbase >> 10;
                const int sb = rowbase & 1023;
                bf16x4 vv;
#pragma unroll
                for (int r = 0; r < 4; ++r) vv[r] = (__bf16)(acc[am][an][r] + bias);
                *(bf16x4*)&vtbuf[((size_t)(bb * 1024 + col)) * 1024 + sb] = vv;
            } else if (mode == 0) {
#pragma unroll
                for (int r = 0; r < 4; ++r)
                    qbuf[(size_t)(rowbase + r) * DMODEL + col] =
                        (__bf16)((acc[am][an][r] + bias) * 0.125f);  // attn scale
            } else {
#pragma unroll
                for (int r = 0; r < 4; ++r)
                    keffbuf[(size_t)(rowbase + r) * DMODEL + col] =
                        (__bf16)(acc[am][an][r] + bias);
            }
        }
    }
}

// ---------------------------------------------------------------------------
// out-proj: out = attn @ Wo^T + bo (fp32). 64x128 tile, grid 512 (2/CU).
// Wave tile 32x64: 2x4 fragments. m97 staging + 2-bit T2 swizzle
// (64B rows = 4 slots: byte ^= ((row&3)<<4)). (unchanged this round)
// ---------------------------------------------------------------------------
__global__ __launch_bounds__(256) void oproj_kernel(
    const __bf16* __restrict__ attnb, const __bf16* __restrict__ Wob,
    const float* __restrict__ bo, float* __restrict__ outb)
{
    const int tile = blockIdx.x;          // 512 = 64 (m) x 8 (n)
    const int m0 = (tile >> 3) << 6;
    const int n0 = (tile & 7) << 7;

    __shared__ __align__(16) __bf16 Alds[64 * 32];
    __shared__ __align__(16) __bf16 Blds[128 * 32];

    const int t    = threadIdx.x;
    const int w    = t >> 6;
    const int lane = t & 63;
    const int l15  = lane & 15;
    const int quad = lane >> 4;
    const int wm   = (w >> 1) << 5;   // 2 m-waves x 2 n-waves
    const int wn   = (w & 1) << 6;
    const int srow = t >> 2;
    // source col swizzle: byte = (t&3)*16 ^ ((srow&3)<<4)
    const int scol = ((((t & 3) * 16) ^ (((t >> 2) & 3) << 4)) >> 1);
    // read col swizzle: rows are ...*16 + l15 -> row&3 == l15&3
    const int rcol = (((quad * 16) ^ ((l15 & 3) << 4)) >> 1);

    const __bf16* gA  = attnb + (size_t)(m0 + srow) * DMODEL + scol;
    const __bf16* gB0 = Wob + (size_t)(n0 + srow) * DMODEL + scol;
    const __bf16* gB1 = Wob + (size_t)(n0 + 64 + srow) * DMODEL + scol;
    __bf16* lA  = &Alds[w * 512];
    __bf16* lB0 = &Blds[w * 512];
    __bf16* lB1 = &Blds[2048 + w * 512];

    f32x4 acc[2][4];
    for (int i = 0; i < 2; ++i)
        for (int j = 0; j < 4; ++j)
            acc[i][j] = {0.f, 0.f, 0.f, 0.f};

    for (int kk = 0; kk < 32; ++kk) {
        const int k0 = kk * 32;
        ASYNC_LOAD16(gA + k0, lA);
        ASYNC_LOAD16(gB0 + k0, lB0);
        ASYNC_LOAD16(gB1 + k0, lB1);
        __syncthreads();

        bf16x8 af[2], bfr[4];
        for (int i = 0; i < 2; ++i)
            af[i] = *(const bf16x8*)&Alds[(wm + i * 16 + l15) * 32 + rcol];
        for (int j = 0; j < 4; ++j)
            bfr[j] = *(const bf16x8*)&Blds[(wn + j * 16 + l15) * 32 + rcol];

        for (int i = 0; i < 2; ++i)
            for (int j = 0; j < 4; ++j)
                acc[i][j] = __builtin_amdgcn_mfma_f32_16x16x32_bf16(
                    af[i], bfr[j], acc[i][j], 0, 0, 0);
        __syncthreads();
    }

    for (int j = 0; j < 4; ++j) {
        const int col = n0 + wn + j * 16 + l15;
        const float bias = bo[col];
        for (int i = 0; i < 2; ++i) {
            const int rowbase = m0 + wm + i * 16 + quad * 4;
            for (int r = 0; r < 4; ++r)
                outb[(size_t)(rowbase + r) * DMODEL + col] = acc[i][j][r] + bias;
        }
    }
}

// ---------------------------------------------------------------------------
// flash attention: one block per (b, h, 64 q-rows). causal. q pre-scaled by
// 0.125. Shift-free softmax (bounded scores), rowsum via ones-MFMA.
// [72]-padded LDS rows are bank-spread — unchanged this round.
// ---------------------------------------------------------------------------
__global__ __launch_bounds__(256) void attn_kernel(
    const __bf16* __restrict__ qbuf, const __bf16* __restrict__ keffbuf,
    const __bf16* __restrict__ vtbuf, __bf16* __restrict__ attnbuf)
{
    const int bh = blockIdx.y;
    const int b  = bh >> 4;
    const int h  = bh & 15;
    const int qt = blockIdx.x;
    const int q0 = qt * 64;

    __shared__ __align__(16) __bf16 Klds[64][72];
    __shared__ __align__(16) __bf16 Vlds[64][72];
    __shared__ __align__(16) __bf16 Plds[4][16][72];

    const int t    = threadIdx.x;
    const int w    = t >> 6;
    const int lane = t & 63;
    const int l15  = lane & 15;
    const int quad = lane >> 4;

    const __bf16* qbase =
        qbuf + (size_t)(b * 1024 + q0 + w * 16 + l15) * DMODEL + h * 64;
    bf16x8 qf0 = *(const bf16x8*)&qbase[quad * 8];
    bf16x8 qf1 = *(const bf16x8*)&qbase[32 + quad * 8];

    bf16x8 ones;
    for (int i = 0; i < 8; ++i) ones[i] = (__bf16)1.0f;

    f32x4 o[4];
    for (int i = 0; i < 4; ++i) o[i] = {0.f, 0.f, 0.f, 0.f};
    f32x4 lacc = {0.f, 0.f, 0.f, 0.f};

    const int srow = t >> 2;
    const int scol = (t & 3) * 16;

    const __bf16* kbase = keffbuf + (size_t)(b * 1024) * DMODEL + h * 64;
    const __bf16* vtb   = vtbuf + (size_t)(b * 1024 + h * 64) * 1024;

    for (int j = 0; j <= qt; ++j) {
        const __bf16* kg = kbase + (size_t)(j * 64 + srow) * DMODEL + scol;
        *(bf16x8*)&Klds[srow][scol]     = *(const bf16x8*)kg;
        *(bf16x8*)&Klds[srow][scol + 8] = *(const bf16x8*)(kg + 8);
        const __bf16* vg = vtb + (size_t)srow * 1024 + j * 64 + scol;
        *(bf16x8*)&Vlds[srow][scol]     = *(const bf16x8*)vg;
        *(bf16x8*)&Vlds[srow][scol + 8] = *(const bf16x8*)(vg + 8);
        __syncthreads();

        f32x4 sc[4];
        for (int nt = 0; nt < 4; ++nt) {
            sc[nt] = {0.f, 0.f, 0.f, 0.f};
            bf16x8 kf0 = *(const bf16x8*)&Klds[nt * 16 + l15][quad * 8];
            bf16x8 kf1 = *(const bf16x8*)&Klds[nt * 16 + l15][32 + quad * 8];
            sc[nt] = __builtin_amdgcn_mfma_f32_16x16x32_bf16(qf0, kf0, sc[nt], 0, 0, 0);
            sc[nt] = __builtin_amdgcn_mfma_f32_16x16x32_bf16(qf1, kf1, sc[nt], 0, 0, 0);
        }

        // causal mask (diagonal tile only): -1e30 -> exp underflows to 0
        if (j == qt) {
            const int qrow_base = q0 + w * 16 + quad * 4;
            for (int nt = 0; nt < 4; ++nt) {
                const int kcol = j * 64 + nt * 16 + l15;
                for (int r = 0; r < 4; ++r)
                    if (kcol > qrow_base + r) sc[nt][r] = -1e30f;
            }
        }

        // shift-free exp
        for (int nt = 0; nt < 4; ++nt)
            for (int r = 0; r < 4; ++r)
                sc[nt][r] = __expf(sc[nt][r]);

        // P -> per-wave LDS (C-layout), read back as A-layout frags
        for (int nt = 0; nt < 4; ++nt)
            for (int r = 0; r < 4; ++r)
                Plds[w][quad * 4 + r][nt * 16 + l15] = (__bf16)sc[nt][r];
        asm volatile("s_waitcnt lgkmcnt(0)" ::: "memory");

        bf16x8 pf0 = *(const bf16x8*)&Plds[w][l15][quad * 8];
        bf16x8 pf1 = *(const bf16x8*)&Plds[w][l15][32 + quad * 8];

        // row-sum via ones-MFMA (replicated over lanes, no shuffles)
        lacc = __builtin_amdgcn_mfma_f32_16x16x32_bf16(pf0, ones, lacc, 0, 0, 0);
        lacc = __builtin_amdgcn_mfma_f32_16x16x32_bf16(pf1, ones, lacc, 0, 0, 0);

        for (int nd = 0; nd < 4; ++nd) {
            bf16x8 vf0 = *(const bf16x8*)&Vlds[nd * 16 + l15][quad * 8];
            bf16x8 vf1 = *(const bf16x8*)&Vlds[nd * 16 + l15][32 + quad * 8];
            o[nd] = __builtin_amdgcn_mfma_f32_16x16x32_bf16(pf0, vf0, o[nd], 0, 0, 0);
            o[nd] = __builtin_amdgcn_mfma_f32_16x16x32_bf16(pf1, vf1, o[nd], 0, 0, 0);
        }
        __syncthreads();
    }

    float rinv[4];
    for (int r = 0; r < 4; ++r) rinv[r] = 1.0f / lacc[r];
    for (int nd = 0; nd < 4; ++nd) {
        for (int r = 0; r < 4; ++r) {
            const int row = q0 + w * 16 + quad * 4 + r;
            attnbuf[(size_t)(b * 1024 + row) * DMODEL + h * 64 + nd * 16 + l15] =
                (__bf16)(o[nd][r] * rinv[r]);
        }
    }
}

extern "C" void kernel_launch(void* const* d_in, const int* in_sizes, int n_in,
                              void* d_out, int out_size, void* d_ws, size_t ws_size,
                              hipStream_t stream) {
    const float* x     = (const float*)d_in[0];
    const int* bar     = (const int*)d_in[2];
    const int* beat    = (const int*)d_in[3];
    const float* Wq    = (const float*)d_in[4];
    const float* bq    = (const float*)d_in[5];
    const float* Wk    = (const float*)d_in[6];
    const float* bk    = (const float*)d_in[7];
    const float* Wv    = (const float*)d_in[8];
    const float* bv    = (const float*)d_in[9];
    const float* Wbar  = (const float*)d_in[10];
    const float* bbar  = (const float*)d_in[11];
    const float* Wbeat = (const float*)d_in[12];
    const float* bbeat = (const float*)d_in[13];
    const float* Wo    = (const float*)d_in[14];
    const float* bo    = (const float*)d_in[15];

    const size_t M1 = (size_t)1 << 20;
    __bf16* xb     = (__bf16*)d_ws;       // 4M
    __bf16* Wqb    = xb + 4 * M1;         // 6 x 1M weights
    __bf16* Wkb    = Wqb + M1;
    __bf16* Wvb    = Wkb + M1;
    __bf16* Wbarb  = Wvb + M1;
    __bf16* Wbeatb = Wbarb + M1;
    __bf16* Wob    = Wbeatb + M1;
    __bf16* qbuf   = Wob + M1;            // 4M
    __bf16* keff   = qbuf + 4 * M1;       // 4M
    __bf16* vt     = keff + 4 * M1;       // 4M
    __bf16* attn   = vt + 4 * M1;         // 4M
    float*  outb   = (float*)d_out;

    cvt_kernel<<<5120, 256, 0, stream>>>(x, Wq, Wk, Wv, Wbar, Wbeat, Wo, xb);

    gemm8p_kernel<<<384, 512, 0, stream>>>(
        xb, Wqb, Wkb, Wvb, Wbarb, Wbeatb,
        bq, bk, bv, bbar, bbeat, bar, beat,
        qbuf, keff, vt);

    attn_kernel<<<dim3(16, 64), 256, 0, stream>>>(qbuf, keff, vt, attn);

    oproj_kernel<<<512, 256, 0, stream>>>(attn, Wob, bo, outb);
}

// Round 4
// 205.497 us; speedup vs baseline: 1.1913x; 1.0779x over previous
//
#include <hip/hip_runtime.h>
#include <hip/hip_bf16.h>

// B=4, S=1024, D=1024, H=16, HD=64 — tokens M=4096, feature K=1024
// fp32 inputs -> bf16 convert pass -> all GEMMs/attention in bf16 MFMA
// (fp32 accumulate) -> fp32 output.
// ROUND 4: attention rewrite. gemm8p is 58.8 of 221.5 µs — the hidden
// ~160 µs is cvt+attn+oproj; attn is the prime suspect (no prefetch,
// QBLK=64, latency-exposed K/V loads). New attn: QBLK=128, 8 waves,
// K/V double-buffered via global_load_lds w=16 + T2 XOR swizzle
// (slot ^= row&7 within 128B rows), counted vmcnt(2) one-tile-ahead
// prefetch, complement qt-pairing for per-CU balance (every CU: 18 iters).
// gemm8p / oproj / cvt unchanged from round 3 (verified).

typedef __bf16 bf16x8 __attribute__((ext_vector_type(8)));
typedef __bf16 bf16x4 __attribute__((ext_vector_type(4)));
typedef float  f32x4  __attribute__((ext_vector_type(4)));

#define DMODEL 1024

#define ASYNC_LOAD16(gp, lp)                                                  \
    __builtin_amdgcn_global_load_lds(                                         \
        (const __attribute__((address_space(1))) unsigned int*)(gp),          \
        (__attribute__((address_space(3))) unsigned int*)(lp), 16, 0, 0)

// ---------------------------------------------------------------------------
// fp32 -> bf16 conversion: x (4M) + 6 weights (1M each); Wbar pre-scaled by
// 0.2 and Wbeat by 0.1 (folds the score-bias scales into the GEMM).
// ---------------------------------------------------------------------------
__global__ __launch_bounds__(256) void cvt_kernel(
    const float* __restrict__ x,
    const float* __restrict__ Wq, const float* __restrict__ Wk,
    const float* __restrict__ Wv, const float* __restrict__ Wbar,
    const float* __restrict__ Wbeat, const float* __restrict__ Wo,
    __bf16* __restrict__ dst)
{
    const int g = blockIdx.x * 256 + threadIdx.x;
    const size_t e = (size_t)g * 8;
    const int seg = (int)(e >> 20);
    const float* src; size_t off; float s = 1.0f;
    if (seg < 4)       { src = x;     off = e; }
    else if (seg == 4) { src = Wq;    off = e - ((size_t)4 << 20); }
    else if (seg == 5) { src = Wk;    off = e - ((size_t)5 << 20); }
    else if (seg == 6) { src = Wv;    off = e - ((size_t)6 << 20); }
    else if (seg == 7) { src = Wbar;  off = e - ((size_t)7 << 20); s = 0.2f; }
    else if (seg == 8) { src = Wbeat; off = e - ((size_t)8 << 20); s = 0.1f; }
    else               { src = Wo;    off = e - ((size_t)9 << 20); }
    const float4 a = *(const float4*)&src[off];
    const float4 b = *(const float4*)&src[off + 4];
    bf16x8 v;
    v[0] = (__bf16)(a.x * s); v[1] = (__bf16)(a.y * s);
    v[2] = (__bf16)(a.z * s); v[3] = (__bf16)(a.w * s);
    v[4] = (__bf16)(b.x * s); v[5] = (__bf16)(b.y * s);
    v[6] = (__bf16)(b.z * s); v[7] = (__bf16)(b.w * s);
    *(bf16x8*)&dst[e] = v;
}

// ---------------------------------------------------------------------------
// 2-phase / 3-buffer GEMM (unchanged from round 3): BM=128, BN=256, BK=64,
// 8 waves, 144KB LDS, T2 swizzle (0 bank conflicts verified), one counted
// vmcnt(6)/K-tile at 2-K-tile issue-to-wait distance.
// ---------------------------------------------------------------------------

#define SWZ_COL(r_, ks_) \
    (((((ks_) * 64) + quad * 16) ^ (((r_) & 7) << 4)) >> 1)

#define READ_ALL(c_)                                                          \
    do {                                                                      \
        _Pragma("unroll") for (int mh = 0; mh < 2; ++mh)                      \
        _Pragma("unroll") for (int mi = 0; mi < 2; ++mi) {                    \
            const int r_ = ((w >> 2) << 5) + mh * 64 + mi * 16 + l15;         \
            _Pragma("unroll") for (int ks = 0; ks < 2; ++ks)                  \
                af[mh][mi][ks] = *(const bf16x8*)&Alds[(c_) * 8192 +          \
                                        r_ * 64 + SWZ_COL(r_, ks)];           \
        }                                                                     \
        _Pragma("unroll") for (int nh = 0; nh < 2; ++nh)                      \
        _Pragma("unroll") for (int nj = 0; nj < 2; ++nj) {                    \
            const int r_ = ((w & 3) << 5) + nh * 128 + nj * 16 + l15;         \
            _Pragma("unroll") for (int ks = 0; ks < 2; ++ks)                  \
                bfr[nh][nj][ks] = *(const bf16x8*)&Blds[(c_) * 16384 +        \
                                        r_ * 64 + SWZ_COL(r_, ks)];           \
        }                                                                     \
    } while (0)

#define STAGE_A1(bufn_, h_, kt_)                                              \
    do {                                                                      \
        const int tm_ = (kt_) >> 4;                                           \
        const int k0_ = ((kt_) & 15) << 6;                                    \
        const __bf16* ap_ = (tm_ == 0) ? aA0##h_ : (tm_ == 1) ? aA1##h_       \
                                                              : aA2##h_;      \
        ASYNC_LOAD16(ap_ + k0_,                                               \
                     &Alds[(bufn_) * 8192 + (h_) * 4096 + w * 512]);          \
    } while (0)

#define STAGE_B2(bufn_, h_, kt_)                                              \
    do {                                                                      \
        const int tm_ = (kt_) >> 4;                                           \
        const int k0_ = ((kt_) & 15) << 6;                                    \
        const __bf16* wp_ = (tm_ == 0) ? W0 : (tm_ == 1) ? W1 : W2;           \
        ASYNC_LOAD16(wp_ + bro##h_##0 + k0_,                                  \
                     &Blds[(bufn_) * 16384 + (h_) * 8192 + w * 512]);         \
        ASYNC_LOAD16(wp_ + bro##h_##1 + k0_,                                  \
                     &Blds[(bufn_) * 16384 + (h_) * 8192 + 4096 + w * 512]);  \
    } while (0)

#define PHASE_BAR1()                                                          \
    do {                                                                      \
        __builtin_amdgcn_s_barrier();                                         \
        asm volatile("s_waitcnt lgkmcnt(0)" ::: "memory");                    \
    } while (0)

#define MFMA16(nh_)                                                           \
    do {                                                                      \
        __builtin_amdgcn_s_setprio(1);                                        \
        _Pragma("unroll") for (int mh = 0; mh < 2; ++mh)                      \
        _Pragma("unroll") for (int mi = 0; mi < 2; ++mi)                      \
        _Pragma("unroll") for (int nj = 0; nj < 2; ++nj)                      \
        _Pragma("unroll") for (int ks = 0; ks < 2; ++ks) {                    \
            acc[mh * 2 + mi][(nh_) * 2 + nj] =                                \
                __builtin_amdgcn_mfma_f32_16x16x32_bf16(                      \
                    af[mh][mi][ks], bfr[(nh_)][nj][ks],                       \
                    acc[mh * 2 + mi][(nh_) * 2 + nj], 0, 0, 0);               \
        }                                                                     \
        __builtin_amdgcn_s_setprio(0);                                        \
    } while (0)

__global__ __launch_bounds__(512, 2) void gemm8p_kernel(
    const __bf16* __restrict__ xb,
    const __bf16* __restrict__ Wqb, const __bf16* __restrict__ Wkb,
    const __bf16* __restrict__ Wvb, const __bf16* __restrict__ Wbarb,
    const __bf16* __restrict__ Wbeatb,
    const float* __restrict__ bq, const float* __restrict__ bk,
    const float* __restrict__ bv, const float* __restrict__ bbar,
    const float* __restrict__ bbeat,
    const int* __restrict__ bar_idx, const int* __restrict__ beat_idx,
    __bf16* __restrict__ qbuf, __bf16* __restrict__ keffbuf,
    __bf16* __restrict__ vtbuf)
{
    __shared__ __align__(16) __bf16 Alds[3 * 8192];    // 3 buf x [128][64]
    __shared__ __align__(16) __bf16 Blds[3 * 16384];   // 3 buf x [256][64]

    const int bid = blockIdx.x;
    int mode, tk;
    if (bid < 128)      { mode = 1; tk = bid; }        // keff first (3x work)
    else if (bid < 256) { mode = 0; tk = bid - 128; }  // q
    else                { mode = 2; tk = bid - 256; }  // v
    const int m0 = (tk >> 2) << 7;                     // 32 m-tiles x 128
    const int n0 = (tk & 3) << 8;                      // 4 n-tiles x 256
    const int nkt = (mode == 1) ? 48 : 16;

    const int t    = (int)threadIdx.x;
    const int w    = t >> 6;
    const int lane = t & 63;
    const int l15  = lane & 15;
    const int quad = lane >> 4;

    const int srow = t >> 3;                                    // 0..63
    const int scol = ((((t & 7) * 16) ^ (((t >> 3) & 7) << 4)) >> 1);

    const __bf16* aA00 = xb + (size_t)(m0 + srow) * DMODEL + scol;
    const __bf16* aA01 = xb + (size_t)(m0 + 64 + srow) * DMODEL + scol;
    const __bf16* aA10 = aA00; const __bf16* aA11 = aA01;
    const __bf16* aA20 = aA00; const __bf16* aA21 = aA01;
    const __bf16 *W0, *W1, *W2;
    if (mode == 0)      { W0 = W1 = W2 = Wqb; }
    else if (mode == 2) { W0 = W1 = W2 = Wvb; }
    else {
        W0 = Wkb; W1 = Wbarb; W2 = Wbeatb;
        const int bb = m0 & ~1023;                 // batch base row
        const int lr = m0 & 1023;                  // seq-local tile base
        aA10 = xb + (size_t)(bb + bar_idx[lr + srow]) * DMODEL + scol;
        aA11 = xb + (size_t)(bb + bar_idx[lr + 64 + srow]) * DMODEL + scol;
        aA20 = xb + (size_t)(bb + beat_idx[lr + srow]) * DMODEL + scol;
        aA21 = xb + (size_t)(bb + beat_idx[lr + 64 + srow]) * DMODEL + scol;
    }
    const size_t bro00 = (size_t)(n0 + srow) * DMODEL + scol;
    const size_t bro01 = (size_t)(n0 + 64 + srow) * DMODEL + scol;
    const size_t bro10 = (size_t)(n0 + 128 + srow) * DMODEL + scol;
    const size_t bro11 = (size_t)(n0 + 192 + srow) * DMODEL + scol;

    f32x4 acc[4][4];
#pragma unroll
    for (int i = 0; i < 4; ++i)
#pragma unroll
        for (int j = 0; j < 4; ++j)
            acc[i][j] = {0.f, 0.f, 0.f, 0.f};
    bf16x8 af[2][2][2], bfr[2][2][2];

    // prologue: stage tiles 0 and 1 fully; wait tile 0 (vmcnt(6)), publish.
    STAGE_A1(0, 0, 0);
    STAGE_A1(0, 1, 0);
    STAGE_B2(0, 0, 0);
    STAGE_B2(0, 1, 0);
    asm volatile("" ::: "memory");
    STAGE_A1(1, 0, 1);
    STAGE_A1(1, 1, 1);
    STAGE_B2(1, 0, 1);
    STAGE_B2(1, 1, 1);
    asm volatile("s_waitcnt vmcnt(6)" ::: "memory");
    __builtin_amdgcn_s_barrier();

    int rc = 0, fc = 2;
#pragma unroll 1
    for (int kt = 0; kt < nkt; ++kt) {
        const int kn = kt + 2;
        const bool st = (kn < nkt);

        // phA: all ds_reads of tile kt; A-stage of kt+2
        READ_ALL(rc);
        if (st) { STAGE_A1(fc, 0, kn); STAGE_A1(fc, 1, kn); }
        PHASE_BAR1();
        MFMA16(0);

        // phB: B-stage of kt+2; single counted wait; publish tile kt+1
        if (st) { STAGE_B2(fc, 0, kn); STAGE_B2(fc, 1, kn); }
        if (kt < nkt - 2)
            asm volatile("s_waitcnt vmcnt(6)" ::: "memory");
        else if (kt == nkt - 2)
            asm volatile("s_waitcnt vmcnt(0)" ::: "memory");
        PHASE_BAR1();
        MFMA16(1);

        rc = (rc == 2) ? 0 : rc + 1;
        fc = (fc == 2) ? 0 : fc + 1;
    }

    // epilogue: fp32 bias + store
#pragma unroll
    for (int an = 0; an < 4; ++an) {
        const int col = n0 + ((w & 3) << 5) + (an >> 1) * 128 +
                        (an & 1) * 16 + l15;
        float bias;
        if (mode == 0)      bias = bq[col];
        else if (mode == 1) bias = bk[col] + 0.2f * bbar[col] + 0.1f * bbeat[col];
        else                bias = bv[col];
#pragma unroll
        for (int am = 0; am < 4; ++am) {
            const int rowbase = m0 + ((w >> 2) << 5) + (am >> 1) * 64 +
                                (am & 1) * 16 + quad * 4;
            if (mode == 2) {
                const int bb = rowbase >> 10;
                const int sb = rowbase & 1023;
                bf16x4 vv;
#pragma unroll
                for (int r = 0; r < 4; ++r) vv[r] = (__bf16)(acc[am][an][r] + bias);
                *(bf16x4*)&vtbuf[((size_t)(bb * 1024 + col)) * 1024 + sb] = vv;
            } else if (mode == 0) {
#pragma unroll
                for (int r = 0; r < 4; ++r)
                    qbuf[(size_t)(rowbase + r) * DMODEL + col] =
                        (__bf16)((acc[am][an][r] + bias) * 0.125f);  // attn scale
            } else {
#pragma unroll
                for (int r = 0; r < 4; ++r)
                    keffbuf[(size_t)(rowbase + r) * DMODEL + col] =
                        (__bf16)(acc[am][an][r] + bias);
            }
        }
    }
}

// ---------------------------------------------------------------------------
// out-proj: out = attn @ Wo^T + bo (fp32). 64x128 tile, grid 512 (2/CU).
// (unchanged from round 3)
// ---------------------------------------------------------------------------
__global__ __launch_bounds__(256) void oproj_kernel(
    const __bf16* __restrict__ attnb, const __bf16* __restrict__ Wob,
    const float* __restrict__ bo, float* __restrict__ outb)
{
    const int tile = blockIdx.x;          // 512 = 64 (m) x 8 (n)
    const int m0 = (tile >> 3) << 6;
    const int n0 = (tile & 7) << 7;

    __shared__ __align__(16) __bf16 Alds[64 * 32];
    __shared__ __align__(16) __bf16 Blds[128 * 32];

    const int t    = threadIdx.x;
    const int w    = t >> 6;
    const int lane = t & 63;
    const int l15  = lane & 15;
    const int quad = lane >> 4;
    const int wm   = (w >> 1) << 5;   // 2 m-waves x 2 n-waves
    const int wn   = (w & 1) << 6;
    const int srow = t >> 2;
    const int scol = ((((t & 3) * 16) ^ (((t >> 2) & 3) << 4)) >> 1);
    const int rcol = (((quad * 16) ^ ((l15 & 3) << 4)) >> 1);

    const __bf16* gA  = attnb + (size_t)(m0 + srow) * DMODEL + scol;
    const __bf16* gB0 = Wob + (size_t)(n0 + srow) * DMODEL + scol;
    const __bf16* gB1 = Wob + (size_t)(n0 + 64 + srow) * DMODEL + scol;
    __bf16* lA  = &Alds[w * 512];
    __bf16* lB0 = &Blds[w * 512];
    __bf16* lB1 = &Blds[2048 + w * 512];

    f32x4 acc[2][4];
    for (int i = 0; i < 2; ++i)
        for (int j = 0; j < 4; ++j)
            acc[i][j] = {0.f, 0.f, 0.f, 0.f};

    for (int kk = 0; kk < 32; ++kk) {
        const int k0 = kk * 32;
        ASYNC_LOAD16(gA + k0, lA);
        ASYNC_LOAD16(gB0 + k0, lB0);
        ASYNC_LOAD16(gB1 + k0, lB1);
        __syncthreads();

        bf16x8 af[2], bfr[4];
        for (int i = 0; i < 2; ++i)
            af[i] = *(const bf16x8*)&Alds[(wm + i * 16 + l15) * 32 + rcol];
        for (int j = 0; j < 4; ++j)
            bfr[j] = *(const bf16x8*)&Blds[(wn + j * 16 + l15) * 32 + rcol];

        for (int i = 0; i < 2; ++i)
            for (int j = 0; j < 4; ++j)
                acc[i][j] = __builtin_amdgcn_mfma_f32_16x16x32_bf16(
                    af[i], bfr[j], acc[i][j], 0, 0, 0);
        __syncthreads();
    }

    for (int j = 0; j < 4; ++j) {
        const int col = n0 + wn + j * 16 + l15;
        const float bias = bo[col];
        for (int i = 0; i < 2; ++i) {
            const int rowbase = m0 + wm + i * 16 + quad * 4;
            for (int r = 0; r < 4; ++r)
                outb[(size_t)(rowbase + r) * DMODEL + col] = acc[i][j][r] + bias;
        }
    }
}

// ---------------------------------------------------------------------------
// flash attention, ROUND-4 structure: 512 blocks x 512 threads (8 waves).
// QBLK=128 q-rows/block (wave w owns rows q0+w*16..+15). K/V tiles of 64
// double-buffered in LDS, staged by global_load_lds w=16 with T2 swizzle
// (slot ^= row&7 within 128B rows; source pre-swizzled, read swizzled,
// LDS dest linear — rule #21). One-tile-ahead prefetch, counted vmcnt(2).
// Complement qt-pairing (id>>6 -> {0,1,2,3,7,6,5,4}) balances per-CU work
// to exactly 18 iterations. Shift-free softmax + ones-MFMA rowsum as
// before (verified numerics). Causal mask on the last two tiles only.
// ---------------------------------------------------------------------------
#define ATT_SLOT(q_, r_) ((((q_) ^ ((r_) & 7))) * 8)

__global__ __launch_bounds__(512) void attn_kernel(
    const __bf16* __restrict__ qbuf, const __bf16* __restrict__ keffbuf,
    const __bf16* __restrict__ vtbuf, __bf16* __restrict__ attnbuf)
{
    const int id = blockIdx.x;            // 512 = 64 bh x 8 qr
    const int bh = id & 63;
    const int b  = bh >> 4;
    const int h  = bh & 15;
    const int qr = id >> 6;
    const int qt = (qr < 4) ? qr : 11 - qr;   // complement pairing: 18 it/CU
    const int q0 = qt << 7;                   // 128 q-rows per block
    const int NT = 2 * qt + 2;                // causal K/V tiles of 64

    __shared__ __align__(16) __bf16 Klds[2][64 * 64];
    __shared__ __align__(16) __bf16 Vlds[2][64 * 64];
    __shared__ __align__(16) __bf16 Plds[8][16][72];

    const int t    = (int)threadIdx.x;
    const int w    = t >> 6;
    const int lane = t & 63;
    const int l15  = lane & 15;
    const int quad = lane >> 4;

    // staging: 512 thr x 16B = one 64x64 bf16 tile per call.
    // LDS dest linear (t*16B); source slot pre-swizzled (involution).
    const int srow = t >> 3;                           // 0..63
    const int scol = ((t & 7) ^ (srow & 7)) * 8;       // elements, [0,64)

    const __bf16* gK = keffbuf + (size_t)(b * 1024 + srow) * DMODEL +
                       h * 64 + scol;                  // + j*64*DMODEL
    const __bf16* gV = vtbuf + (size_t)(b * 1024 + h * 64 + srow) * 1024 +
                       scol;                           // + j*64

    // q fragments: wave w rows q0 + w*16 + l15
    const __bf16* qbase =
        qbuf + (size_t)(b * 1024 + q0 + w * 16 + l15) * DMODEL + h * 64;
    bf16x8 qf0 = *(const bf16x8*)&qbase[quad * 8];
    bf16x8 qf1 = *(const bf16x8*)&qbase[32 + quad * 8];

    bf16x8 ones;
#pragma unroll
    for (int i = 0; i < 8; ++i) ones[i] = (__bf16)1.0f;

    f32x4 o[4];
#pragma unroll
    for (int i = 0; i < 4; ++i) o[i] = {0.f, 0.f, 0.f, 0.f};
    f32x4 lacc = {0.f, 0.f, 0.f, 0.f};

    // prologue: stage tiles 0 and 1 (NT >= 2 always); publish tile 0.
    ASYNC_LOAD16(gK, &Klds[0][t * 8]);
    ASYNC_LOAD16(gV, &Vlds[0][t * 8]);
    asm volatile("" ::: "memory");
    ASYNC_LOAD16(gK + (size_t)64 * DMODEL, &Klds[1][t * 8]);
    ASYNC_LOAD16(gV + 64, &Vlds[1][t * 8]);
    asm volatile("s_waitcnt vmcnt(2)" ::: "memory");
    __builtin_amdgcn_s_barrier();

#pragma unroll 1
    for (int j = 0; j < NT; ++j) {
        const int cur = j & 1;

        // QK^T: 16 q-rows x 64 kcols per wave, K=64
        f32x4 sc[4];
#pragma unroll
        for (int nt = 0; nt < 4; ++nt) {
            const int row = nt * 16 + l15;
            bf16x8 kf0 = *(const bf16x8*)&Klds[cur][row * 64 +
                                                    ATT_SLOT(quad, row)];
            bf16x8 kf1 = *(const bf16x8*)&Klds[cur][row * 64 +
                                                    ATT_SLOT(quad + 4, row)];
            sc[nt] = {0.f, 0.f, 0.f, 0.f};
            sc[nt] = __builtin_amdgcn_mfma_f32_16x16x32_bf16(qf0, kf0, sc[nt], 0, 0, 0);
            sc[nt] = __builtin_amdgcn_mfma_f32_16x16x32_bf16(qf1, kf1, sc[nt], 0, 0, 0);
        }

        // causal mask: only the last two tiles straddle the diagonal
        if (j >= NT - 2) {
            const int qrow_base = q0 + w * 16 + quad * 4;
#pragma unroll
            for (int nt = 0; nt < 4; ++nt) {
                const int kcol = j * 64 + nt * 16 + l15;
#pragma unroll
                for (int r = 0; r < 4; ++r)
                    if (kcol > qrow_base + r) sc[nt][r] = -1e30f;
            }
        }

        // shift-free exp (scores bounded; q pre-scaled by 0.125)
#pragma unroll
        for (int nt = 0; nt < 4; ++nt)
#pragma unroll
            for (int r = 0; r < 4; ++r)
                sc[nt][r] = __expf(sc[nt][r]);

        // P -> per-wave LDS (C-layout), read back as A-layout frags
#pragma unroll
        for (int nt = 0; nt < 4; ++nt)
#pragma unroll
            for (int r = 0; r < 4; ++r)
                Plds[w][quad * 4 + r][nt * 16 + l15] = (__bf16)sc[nt][r];
        asm volatile("s_waitcnt lgkmcnt(0)" ::: "memory");

        bf16x8 pf0 = *(const bf16x8*)&Plds[w][l15][quad * 8];
        bf16x8 pf1 = *(const bf16x8*)&Plds[w][l15][32 + quad * 8];

        // row-sum via ones-MFMA
        lacc = __builtin_amdgcn_mfma_f32_16x16x32_bf16(pf0, ones, lacc, 0, 0, 0);
        lacc = __builtin_amdgcn_mfma_f32_16x16x32_bf16(pf1, ones, lacc, 0, 0, 0);

        // PV: o[nd] over d-slices, V in [d][s_local] layout (swizzled)
#pragma unroll
        for (int nd = 0; nd < 4; ++nd) {
            const int row = nd * 16 + l15;
            bf16x8 vf0 = *(const bf16x8*)&Vlds[cur][row * 64 +
                                                    ATT_SLOT(quad, row)];
            bf16x8 vf1 = *(const bf16x8*)&Vlds[cur][row * 64 +
                                                    ATT_SLOT(quad + 4, row)];
            o[nd] = __builtin_amdgcn_mfma_f32_16x16x32_bf16(pf0, vf0, o[nd], 0, 0, 0);
            o[nd] = __builtin_amdgcn_mfma_f32_16x16x32_bf16(pf1, vf1, o[nd], 0, 0, 0);
        }

        __syncthreads();   // all waves done reading buf[cur]
        if (j + 2 < NT) {  // prefetch tile j+2 into the buffer just freed
            ASYNC_LOAD16(gK + (size_t)(j + 2) * 64 * DMODEL, &Klds[cur][t * 8]);
            ASYNC_LOAD16(gV + (size_t)(j + 2) * 64, &Vlds[cur][t * 8]);
        }
        if (j + 1 < NT) {
            if (j + 2 < NT)
                asm volatile("s_waitcnt vmcnt(2)" ::: "memory");
            else
                asm volatile("s_waitcnt vmcnt(0)" ::: "memory");
            __builtin_amdgcn_s_barrier();   // buf[cur^1] (tile j+1) ready
        }
    }

    float rinv[4];
#pragma unroll
    for (int r = 0; r < 4; ++r) rinv[r] = 1.0f / lacc[r];
#pragma unroll
    for (int nd = 0; nd < 4; ++nd) {
#pragma unroll
        for (int r = 0; r < 4; ++r) {
            const int row = q0 + w * 16 + quad * 4 + r;
            attnbuf[(size_t)(b * 1024 + row) * DMODEL + h * 64 + nd * 16 + l15] =
                (__bf16)(o[nd][r] * rinv[r]);
        }
    }
}

extern "C" void kernel_launch(void* const* d_in, const int* in_sizes, int n_in,
                              void* d_out, int out_size, void* d_ws, size_t ws_size,
                              hipStream_t stream) {
    const float* x     = (const float*)d_in[0];
    const int* bar     = (const int*)d_in[2];
    const int* beat    = (const int*)d_in[3];
    const float* Wq    = (const float*)d_in[4];
    const float* bq    = (const float*)d_in[5];
    const float* Wk    = (const float*)d_in[6];
    const float* bk    = (const float*)d_in[7];
    const float* Wv    = (const float*)d_in[8];
    const float* bv    = (const float*)d_in[9];
    const float* Wbar  = (const float*)d_in[10];
    const float* bbar  = (const float*)d_in[11];
    const float* Wbeat = (const float*)d_in[12];
    const float* bbeat = (const float*)d_in[13];
    const float* Wo    = (const float*)d_in[14];
    const float* bo    = (const float*)d_in[15];

    const size_t M1 = (size_t)1 << 20;
    __bf16* xb     = (__bf16*)d_ws;       // 4M
    __bf16* Wqb    = xb + 4 * M1;         // 6 x 1M weights
    __bf16* Wkb    = Wqb + M1;
    __bf16* Wvb    = Wkb + M1;
    __bf16* Wbarb  = Wvb + M1;
    __bf16* Wbeatb = Wbarb + M1;
    __bf16* Wob    = Wbeatb + M1;
    __bf16* qbuf   = Wob + M1;            // 4M
    __bf16* keff   = qbuf + 4 * M1;       // 4M
    __bf16* vt     = keff + 4 * M1;       // 4M
    __bf16* attn   = vt + 4 * M1;         // 4M
    float*  outb   = (float*)d_out;

    cvt_kernel<<<5120, 256, 0, stream>>>(x, Wq, Wk, Wv, Wbar, Wbeat, Wo, xb);

    gemm8p_kernel<<<384, 512, 0, stream>>>(
        xb, Wqb, Wkb, Wvb, Wbarb, Wbeatb,
        bq, bk, bv, bbar, bbeat, bar, beat,
        qbuf, keff, vt);

    attn_kernel<<<512, 512, 0, stream>>>(qbuf, keff, vt, attn);

    oproj_kernel<<<512, 256, 0, stream>>>(attn, Wob, bo, outb);
}